// Round 4
// baseline (1384.927 us; speedup 1.0000x reference)
//
#include <hip/hip_runtime.h>

// Problem constants
constexpr int S = 8, B = 128, T = 256, N = 128;
constexpr int L = 64, Hh = 128, Hd = 64, Hl = 128;
constexpr int BT = B * T;

#define DEVFN __device__ __forceinline__

typedef float    f32x4_t __attribute__((ext_vector_type(4)));
typedef _Float16 f16x8_t __attribute__((ext_vector_type(8)));
typedef _Float16 f16x4_t __attribute__((ext_vector_type(4)));

DEVFN float softplus_f(float x) {            // accurate (prologue only)
    return (x > 0.f) ? (x + log1pf(expf(-x))) : log1pf(expf(x));
}
DEVFN float softplus_fast(float x) {         // branchless, native trans
    return fmaxf(x, 0.f) + __logf(1.f + __expf(-fabsf(x)));
}
DEVFN float fast_tanh(float x) {
    float ex = __builtin_exp2f(x * 2.885390081777927f);
    return 1.f - 2.f / (ex + 1.f);
}

// ---------------------------------------------------------------------------
// Kernel A: per (b,t) row:  h = tanh(y @ W_be + b_be);  A = h @ W1a + b_le1
// ---------------------------------------------------------------------------
__global__ __launch_bounds__(256) void kA(
        const float* __restrict__ y,
        const float* __restrict__ W_be, const float* __restrict__ b_be,
        const float* __restrict__ W_le1, const float* __restrict__ b_le1,
        float* __restrict__ A, float* __restrict__ h0) {
    __shared__ float Wb[128 * 128];
    __shared__ float Wa[128 * 128];
    __shared__ float yt[128][16];
    __shared__ float ht[128][16];
    __shared__ float bbe[128], ble1[128];

    const int tid = threadIdx.x;
    {
        const float4* s1 = (const float4*)W_be;
        const float4* s2 = (const float4*)W_le1;   // rows 0..127 = W1a
        float4* d1 = (float4*)Wb;
        float4* d2 = (float4*)Wa;
        for (int i = tid; i < 4096; i += 256) { d1[i] = s1[i]; d2[i] = s2[i]; }
    }
    if (tid < 128) { bbe[tid] = b_be[tid]; ble1[tid] = b_le1[tid]; }

    const int bt0 = blockIdx.x * 16;
    {
        const float4* ys = (const float4*)(y + (size_t)bt0 * 128);
        for (int q = tid; q < 512; q += 256) {
            float4 v = ys[q];
            int r = q >> 5, n4 = (q & 31) * 4;
            yt[n4 + 0][r] = v.x; yt[n4 + 1][r] = v.y;
            yt[n4 + 2][r] = v.z; yt[n4 + 3][r] = v.w;
        }
    }
    __syncthreads();

    const int j = tid & 127, rh = tid >> 7;
    float acc[8];

    #pragma unroll
    for (int s = 0; s < 8; s++) acc[s] = bbe[j];
    #pragma unroll 4
    for (int k = 0; k < 128; k++) {
        float w = Wb[k * 128 + j];
        float4 a0 = *(const float4*)&yt[k][rh * 8];
        float4 a1 = *(const float4*)&yt[k][rh * 8 + 4];
        acc[0] += w * a0.x; acc[1] += w * a0.y; acc[2] += w * a0.z; acc[3] += w * a0.w;
        acc[4] += w * a1.x; acc[5] += w * a1.y; acc[6] += w * a1.z; acc[7] += w * a1.w;
    }
    #pragma unroll
    for (int s = 0; s < 8; s++) ht[j][rh * 8 + s] = tanhf(acc[s]);
    __syncthreads();

    #pragma unroll
    for (int s = 0; s < 8; s++) acc[s] = ble1[j];
    #pragma unroll 4
    for (int k = 0; k < 128; k++) {
        float w = Wa[k * 128 + j];
        float4 a0 = *(const float4*)&ht[k][rh * 8];
        float4 a1 = *(const float4*)&ht[k][rh * 8 + 4];
        acc[0] += w * a0.x; acc[1] += w * a0.y; acc[2] += w * a0.z; acc[3] += w * a0.w;
        acc[4] += w * a1.x; acc[5] += w * a1.y; acc[6] += w * a1.z; acc[7] += w * a1.w;
    }
    #pragma unroll
    for (int s = 0; s < 8; s++) {
        int r = rh * 8 + s;
        A[(size_t)(bt0 + r) * 128 + j] = acc[s];
    }
    if (rh == 0 && (bt0 & 255) == 0) {
        h0[(bt0 >> 8) * 128 + j] = ht[j][0];
    }
}

// ---------------------------------------------------------------------------
// Kernel B: initial step (t=0). Writes kl0 to slab 0, zeros slabs 1..31.
// ---------------------------------------------------------------------------
__global__ __launch_bounds__(128) void kB(
        const float* __restrict__ h0, const float* __restrict__ W_ic,
        const float* __restrict__ b_ic, const float* __restrict__ m_0,
        const float* __restrict__ log_Q_0, const float* __restrict__ eps0,
        float* __restrict__ zout, float* __restrict__ klw) {
    __shared__ float hr[128];
    __shared__ float mp[128];
    const int b = blockIdx.x, tid = threadIdx.x;
    hr[tid] = h0[b * 128 + tid];
    __syncthreads();
    float acc = b_ic[tid];
    #pragma unroll 8
    for (int k = 0; k < 128; k++) acc += hr[k] * W_ic[k * 128 + tid];
    mp[tid] = acc;
    __syncthreads();

    float term = 0.f;
    if (tid < 64) {
        float m = mp[tid];
        float P = softplus_f(mp[tid + 64]);
        float sq = sqrtf(P);
        #pragma unroll
        for (int s = 0; s < 8; s++) {
            float e = eps0[((size_t)s * B + b) * 64 + tid];
            zout[(((size_t)s * B + b) * T + 0) * 64 + tid] = m + sq * e;
        }
        float Q0 = softplus_f(log_Q_0[tid]);
        float d = m - m_0[tid];
        term = 0.5f * (logf(Q0) - logf(P) + (P + d * d) / Q0 - 1.f);
    }
    #pragma unroll
    for (int off = 32; off; off >>= 1) term += __shfl_down(term, off);
    if (tid == 0) klw[(size_t)b * T] = term;
    else if (tid < 32) klw[(size_t)tid * BT + (size_t)b * T] = 0.f;
}

// ---------------------------------------------------------------------------
// Kernel C (MFMA, NS=1): scan t=1..T-1.
// 1024 blocks = (b = bid>>3, s = bid&7); 256 threads = 4 waves; 4 blocks/CU.
// MFMA fragment convention (verified R2/R3):
//   lane l: lo=l&15, hi=l>>4; A[row=lo][k=8hi+e], B[k=8hi+e][col=lo]
//   D: col(sample)=lo, row(outcol offset)=4hi+reg
// Single sample -> producer lanes (lo==0) own complete in-lane results:
// activation and epilogue run in-register, only 2 barriers per step,
// no f32 staging. Per-wave KL partials stored to 32 ws slabs (off-chain).
// ---------------------------------------------------------------------------
__global__ __launch_bounds__(256, 4) void kC(
        const float* __restrict__ Aglob,
        const float* __restrict__ W_le1, const float* __restrict__ W_le2,
        const float* __restrict__ b_le2,
        const float* __restrict__ W_dyn1, const float* __restrict__ b_dyn1,
        const float* __restrict__ W_dyn2, const float* __restrict__ b_dyn2,
        const float* __restrict__ log_Q, const float* __restrict__ eps,
        float* __restrict__ zout, float* __restrict__ klw) {
    __shared__ alignas(16) _Float16 zSm[16][72];    // row 0 live, rows 1..15 zero
    __shared__ alignas(16) _Float16 hidS[16][136];
    __shared__ alignas(16) _Float16 gS[16][72];

    const int tid = threadIdx.x;
    const int b = blockIdx.x >> 3, s = blockIdx.x & 7;
    const int w = tid >> 6, l = tid & 63;
    const int lo = l & 15, hi = l >> 4;
    const int cg = 16 * w + 4 * hi;     // col base for dyn/m/P/mu/g
    const bool act = (lo == 0);

    // ---- zero f16 LDS (rows >=1 stay zero forever) ----
    {
        _Float16* p1 = &zSm[0][0];
        _Float16* p2 = &hidS[0][0];
        _Float16* p3 = &gS[0][0];
        for (int i = tid; i < 16 * 72; i += 256) { p1[i] = (_Float16)0.f; p3[i] = (_Float16)0.f; }
        for (int i = tid; i < 16 * 136; i += 256) p2[i] = (_Float16)0.f;
    }

    // ---- static weight fragments (64 VGPRs) ----
    f16x8_t a1[2][2], a2[2][4], a3[2], a4[2];
    #pragma unroll
    for (int ct = 0; ct < 2; ++ct)
        #pragma unroll
        for (int kt = 0; kt < 2; ++kt) {
            f16x8_t f;
            #pragma unroll
            for (int e = 0; e < 8; ++e)
                f[e] = (_Float16)W_le1[(size_t)(128 + kt * 32 + 8 * hi + e) * 128 + (32 * w + 16 * ct + lo)];
            a1[ct][kt] = f;
        }
    #pragma unroll
    for (int ct = 0; ct < 2; ++ct) {
        const int col = (ct == 0 ? 16 * w : 64 + 16 * w) + lo;
        #pragma unroll
        for (int kt = 0; kt < 4; ++kt) {
            f16x8_t f;
            #pragma unroll
            for (int e = 0; e < 8; ++e)
                f[e] = (_Float16)W_le2[(size_t)(kt * 32 + 8 * hi + e) * 128 + col];
            a2[ct][kt] = f;
        }
    }
    #pragma unroll
    for (int kt = 0; kt < 2; ++kt) {
        f16x8_t f, g;
        #pragma unroll
        for (int e = 0; e < 8; ++e) {
            f[e] = (_Float16)W_dyn1[(size_t)(kt * 32 + 8 * hi + e) * 64 + (16 * w + lo)];
            g[e] = (_Float16)W_dyn2[(size_t)(kt * 32 + 8 * hi + e) * 64 + (16 * w + lo)];
        }
        a3[kt] = f; a4[kt] = g;
    }

    // ---- loop-invariant per-lane constants ----
    const f32x4_t bm   = *(const f32x4_t*)&b_le2[cg];
    const f32x4_t bp   = *(const f32x4_t*)&b_le2[64 + cg];
    const f32x4_t bmu  = *(const f32x4_t*)&b_dyn2[cg];
    const f32x4_t bd1v = *(const f32x4_t*)&b_dyn1[cg];
    f32x4_t invQ;
    #pragma unroll
    for (int r = 0; r < 4; ++r) invQ[r] = 1.f / softplus_f(log_Q[cg + r]);

    // ---- pointers (active lanes) ----
    const float* ap = Aglob + ((size_t)b * T + 1) * 128 + 32 * w + 4 * hi;
    const float* ep = eps + ((size_t)s * B + b) * 64 + cg;               // t=1
    float*       zp = zout + (((size_t)s * B + b) * T + 1) * 64 + cg;
    float*       kp = klw + (size_t)(s * 4 + w) * BT + (size_t)b * T;

    __syncthreads();
    // ---- stage z0 ----
    if (tid < 64)
        zSm[0][tid] = (_Float16)zout[(((size_t)s * B + b) * T + 0) * 64 + tid];
    __syncthreads();

    // ---- software-pipelined prefetch (t=1) ----
    f32x4_t aN0 = {0,0,0,0}, aN1 = {0,0,0,0}, eN = {0,0,0,0};
    if (act) {
        aN0 = *(const f32x4_t*)ap;
        aN1 = *(const f32x4_t*)(ap + 16);
        eN  = *(const f32x4_t*)ep;
    }

    for (int t = 1; t < T; ++t) {
        const f32x4_t aC0 = aN0, aC1 = aN1, eC = eN;

        // ---- phase A MFMAs: z@W1b ; z@Wd1 ----
        const f16x8_t bz0 = *(const f16x8_t*)&zSm[lo][8 * hi];
        const f16x8_t bz1 = *(const f16x8_t*)&zSm[lo][32 + 8 * hi];

        f32x4_t acc1a = {0.f,0.f,0.f,0.f}, acc1b = {0.f,0.f,0.f,0.f}, acc3 = {0.f,0.f,0.f,0.f};
        acc1a = __builtin_amdgcn_mfma_f32_16x16x32_f16(a1[0][0], bz0, acc1a, 0, 0, 0);
        acc1b = __builtin_amdgcn_mfma_f32_16x16x32_f16(a1[1][0], bz0, acc1b, 0, 0, 0);
        acc3  = __builtin_amdgcn_mfma_f32_16x16x32_f16(a3[0],    bz0, acc3,  0, 0, 0);
        acc1a = __builtin_amdgcn_mfma_f32_16x16x32_f16(a1[0][1], bz1, acc1a, 0, 0, 0);
        acc1b = __builtin_amdgcn_mfma_f32_16x16x32_f16(a1[1][1], bz1, acc1b, 0, 0, 0);
        acc3  = __builtin_amdgcn_mfma_f32_16x16x32_f16(a3[1],    bz1, acc3,  0, 0, 0);

        // issue next-step global prefetch early (covered by ~1 full step)
        if (act && t < T - 1) {
            ap += 128; ep += (size_t)S * B * 64;
            aN0 = *(const f32x4_t*)ap;
            aN1 = *(const f32x4_t*)(ap + 16);
            eN  = *(const f32x4_t*)ep;
        }

        // ---- in-lane activation (producer lanes) ----
        if (act) {
            f16x4_t hv0, hv1, gv;
            #pragma unroll
            for (int r = 0; r < 4; ++r) {
                hv0[r] = (_Float16)fast_tanh(acc1a[r] + aC0[r]);
                hv1[r] = (_Float16)fast_tanh(acc1b[r] + aC1[r]);
                gv[r]  = (_Float16)fast_tanh(acc3[r] + bd1v[r]);
            }
            *(f16x4_t*)&hidS[0][32 * w + 4 * hi]      = hv0;
            *(f16x4_t*)&hidS[0][32 * w + 16 + 4 * hi] = hv1;
            *(f16x4_t*)&gS[0][cg]                     = gv;
        }
        __syncthreads();   // (1) hid/g visible

        // ---- phase B MFMAs: hid@W2 ; g@Wd2 ----
        const f16x8_t bh0 = *(const f16x8_t*)&hidS[lo][ 0 + 8 * hi];
        const f16x8_t bh1 = *(const f16x8_t*)&hidS[lo][32 + 8 * hi];
        const f16x8_t bh2 = *(const f16x8_t*)&hidS[lo][64 + 8 * hi];
        const f16x8_t bh3 = *(const f16x8_t*)&hidS[lo][96 + 8 * hi];
        const f16x8_t bg0 = *(const f16x8_t*)&gS[lo][8 * hi];
        const f16x8_t bg1 = *(const f16x8_t*)&gS[lo][32 + 8 * hi];

        f32x4_t accm = {0.f,0.f,0.f,0.f}, accp = {0.f,0.f,0.f,0.f}, acc4 = {0.f,0.f,0.f,0.f};
        accm = __builtin_amdgcn_mfma_f32_16x16x32_f16(a2[0][0], bh0, accm, 0, 0, 0);
        accp = __builtin_amdgcn_mfma_f32_16x16x32_f16(a2[1][0], bh0, accp, 0, 0, 0);
        acc4 = __builtin_amdgcn_mfma_f32_16x16x32_f16(a4[0],    bg0, acc4, 0, 0, 0);
        accm = __builtin_amdgcn_mfma_f32_16x16x32_f16(a2[0][1], bh1, accm, 0, 0, 0);
        accp = __builtin_amdgcn_mfma_f32_16x16x32_f16(a2[1][1], bh1, accp, 0, 0, 0);
        acc4 = __builtin_amdgcn_mfma_f32_16x16x32_f16(a4[1],    bg1, acc4, 0, 0, 0);
        accm = __builtin_amdgcn_mfma_f32_16x16x32_f16(a2[0][2], bh2, accm, 0, 0, 0);
        accp = __builtin_amdgcn_mfma_f32_16x16x32_f16(a2[1][2], bh2, accp, 0, 0, 0);
        accm = __builtin_amdgcn_mfma_f32_16x16x32_f16(a2[0][3], bh3, accm, 0, 0, 0);
        accp = __builtin_amdgcn_mfma_f32_16x16x32_f16(a2[1][3], bh3, accp, 0, 0, 0);

        // ---- in-lane epilogue (producer lanes) ----
        float term = 0.f;
        if (act) {
            f16x4_t zv;
            f32x4_t zst;
            #pragma unroll
            for (int r = 0; r < 4; ++r) {
                float m  = accm[r] + bm[r];
                float P  = softplus_fast(accp[r] + bp[r]);
                float mu = acc4[r] + bmu[r];
                float z  = m + sqrtf(P) * eC[r];
                zst[r] = z;
                zv[r]  = (_Float16)z;
                float d = m - mu;
                term += (P + d * d) * invQ[r] - __logf(P * invQ[r]) - 1.f;
            }
            *(f32x4_t*)zp = zst; zp += 64;
            *(f16x4_t*)&zSm[0][cg] = zv;
        }
        term += __shfl_down(term, 32);
        term += __shfl_down(term, 16);
        if (l == 0) kp[t] = 0.0625f * term;     // 0.5 * 1/8 * wave partial
        __syncthreads();   // (2) zSm visible for next step
    }
}

// ---------------------------------------------------------------------------
// Kernel P: projection + Poisson ell + m_stat.
// ---------------------------------------------------------------------------
__global__ __launch_bounds__(256) void kP(
        const float* __restrict__ zin, const float* __restrict__ C,
        const float* __restrict__ b_c, const float* __restrict__ y,
        float* __restrict__ m_stat, float* __restrict__ ell) {
    __shared__ float Cl[64 * 128];
    __shared__ float bc[128];
    __shared__ float ztl[64][8];
    __shared__ float red4[4];

    const int tid = threadIdx.x;
    {
        const float4* s = (const float4*)C;
        float4* d = (float4*)Cl;
        for (int i = tid; i < 2048; i += 256) d[i] = s[i];
    }
    if (tid < 128) bc[tid] = b_c[tid];

    const int bt0 = blockIdx.x * 8;
    const int n = tid & 127, shh = tid >> 7;

    for (int it = 0; it < 8; it++) {
        const int bt = bt0 + it;
        const int b = bt >> 8, t = bt & 255;
        __syncthreads();
        {
            int s_ = tid >> 6, l_ = tid & 63;
            ztl[l_][s_] = zin[(((size_t)s_ * B + b) * T + t) * 64 + l_];
            int i1 = tid + 256;
            s_ = i1 >> 6; l_ = i1 & 63;
            ztl[l_][s_] = zin[(((size_t)s_ * B + b) * T + t) * 64 + l_];
        }
        __syncthreads();
        if (tid < 64) {
            float4 a = *(const float4*)&ztl[tid][0];
            float4 bq = *(const float4*)&ztl[tid][4];
            m_stat[(size_t)bt * 64 + tid] =
                0.125f * (a.x + a.y + a.z + a.w + bq.x + bq.y + bq.z + bq.w);
        }
        float4 acc = {0.f, 0.f, 0.f, 0.f};
        #pragma unroll 4
        for (int k = 0; k < 64; k++) {
            float c = Cl[k * 128 + n];
            float4 z4 = *(const float4*)&ztl[k][shh * 4];
            acc.x += c * z4.x; acc.y += c * z4.y; acc.z += c * z4.z; acc.w += c * z4.w;
        }
        float bcv = bc[n];
        float yv = y[(size_t)bt * 128 + n];
        int yi = (int)yv;
        float ga = (yi < 2) ? 0.f
                 : ((yi == 2) ? 0.6931471805599453f
                 : ((yi == 3) ? 1.791759469228055f : 3.1780538303479458f));
        float term = 0.f;
        {
            float lr;
            lr = acc.x + bcv; term += yv * lr - __expf(lr) - ga;
            lr = acc.y + bcv; term += yv * lr - __expf(lr) - ga;
            lr = acc.z + bcv; term += yv * lr - __expf(lr) - ga;
            lr = acc.w + bcv; term += yv * lr - __expf(lr) - ga;
        }
        #pragma unroll
        for (int off = 32; off; off >>= 1) term += __shfl_down(term, off);
        if ((tid & 63) == 0) red4[tid >> 6] = term;
        __syncthreads();
        if (tid == 0) ell[bt] = 0.125f * (red4[0] + red4[1] + red4[2] + red4[3]);
    }
}

// ---------------------------------------------------------------------------
// Kernel R1/R2: two-stage loss reduction over 32 kl slabs + ell.
// ---------------------------------------------------------------------------
__global__ __launch_bounds__(256) void kR1(
        const float* __restrict__ klw, const float* __restrict__ ell,
        float* __restrict__ pw) {
    __shared__ float red4[4];
    const int tid = threadIdx.x;
    const int i0 = blockIdx.x * 512 + tid;
    float acc = 0.f;
    #pragma unroll
    for (int ii = 0; ii < 2; ii++) {
        int i = i0 + ii * 256;
        float v = -ell[i];
        #pragma unroll
        for (int sl = 0; sl < 32; sl++) v += klw[(size_t)sl * BT + i];
        acc += v;
    }
    #pragma unroll
    for (int off = 32; off; off >>= 1) acc += __shfl_down(acc, off);
    if ((tid & 63) == 0) red4[tid >> 6] = acc;
    __syncthreads();
    if (tid == 0) pw[blockIdx.x] = red4[0] + red4[1] + red4[2] + red4[3];
}

__global__ __launch_bounds__(64) void kR2(
        const float* __restrict__ pw, float* __restrict__ out0) {
    float v = pw[threadIdx.x];
    #pragma unroll
    for (int off = 32; off; off >>= 1) v += __shfl_down(v, off);
    if (threadIdx.x == 0) out0[0] = v * (1.0f / B);
}

// ---------------------------------------------------------------------------
extern "C" void kernel_launch(void* const* d_in, const int* in_sizes, int n_in,
                              void* d_out, int out_size, void* d_ws, size_t ws_size,
                              hipStream_t stream) {
    const float* y      = (const float*)d_in[0];
    const float* W_be   = (const float*)d_in[2];
    const float* b_be   = (const float*)d_in[3];
    const float* W_ic   = (const float*)d_in[4];
    const float* b_ic   = (const float*)d_in[5];
    const float* W_le1  = (const float*)d_in[6];
    const float* b_le1  = (const float*)d_in[7];
    const float* W_le2  = (const float*)d_in[8];
    const float* b_le2  = (const float*)d_in[9];
    const float* W_dyn1 = (const float*)d_in[10];
    const float* b_dyn1 = (const float*)d_in[11];
    const float* W_dyn2 = (const float*)d_in[12];
    const float* b_dyn2 = (const float*)d_in[13];
    const float* C      = (const float*)d_in[14];
    const float* b_c    = (const float*)d_in[15];
    const float* log_Q  = (const float*)d_in[16];
    const float* m_0    = (const float*)d_in[17];
    const float* log_Q_0= (const float*)d_in[18];
    const float* eps0   = (const float*)d_in[19];
    const float* eps    = (const float*)d_in[20];

    float* out = (float*)d_out;
    float* zo  = out + 1;
    float* ms  = out + 1 + (size_t)S * B * T * L;

    float* ws   = (float*)d_ws;
    float* klw  = ws;                                      // 32*B*T
    float* ellw = klw + (size_t)32 * BT;                   // B*T
    float* pw   = ellw + (size_t)BT;                       // 64
    float* h0   = pw + 64;                                 // B*128
    float* A    = h0 + (size_t)B * 128;                    // B*T*128

    kA<<<2048, 256, 0, stream>>>(y, W_be, b_be, W_le1, b_le1, A, h0);
    kB<<<128, 128, 0, stream>>>(h0, W_ic, b_ic, m_0, log_Q_0, eps0, zo, klw);
    kC<<<1024, 256, 0, stream>>>(A, W_le1, W_le2, b_le2, W_dyn1, b_dyn1,
                                 W_dyn2, b_dyn2, log_Q, eps, zo, klw);
    kP<<<4096, 256, 0, stream>>>(zo, C, b_c, y, ms, ellw);
    kR1<<<64, 256, 0, stream>>>(klw, ellw, pw);
    kR2<<<1, 64, 0, stream>>>(pw, out);
}

// Round 5
// 1341.636 us; speedup vs baseline: 1.0323x; 1.0323x over previous
//
#include <hip/hip_runtime.h>

// Problem constants
constexpr int S = 8, B = 128, T = 256, N = 128;
constexpr int L = 64, Hh = 128, Hd = 64, Hl = 128;
constexpr int BT = B * T;

#define DEVFN __device__ __forceinline__

typedef float    f32x4_t __attribute__((ext_vector_type(4)));
typedef _Float16 f16x8_t __attribute__((ext_vector_type(8)));
typedef _Float16 f16x4_t __attribute__((ext_vector_type(4)));

DEVFN float softplus_f(float x) {            // accurate (prologue only)
    return (x > 0.f) ? (x + log1pf(expf(-x))) : log1pf(expf(x));
}
DEVFN float softplus_fast(float x) {         // branchless, native trans
    return fmaxf(x, 0.f) + __logf(1.f + __expf(-fabsf(x)));
}
DEVFN float fast_tanh(float x) {
    float ex = __builtin_exp2f(x * 2.885390081777927f);
    return 1.f - 2.f / (ex + 1.f);
}

// ---------------------------------------------------------------------------
// Kernel A: per (b,t) row:  h = tanh(y @ W_be + b_be);  A = h @ W1a + b_le1
// ---------------------------------------------------------------------------
__global__ __launch_bounds__(256) void kA(
        const float* __restrict__ y,
        const float* __restrict__ W_be, const float* __restrict__ b_be,
        const float* __restrict__ W_le1, const float* __restrict__ b_le1,
        float* __restrict__ A, float* __restrict__ h0) {
    __shared__ float Wb[128 * 128];
    __shared__ float Wa[128 * 128];
    __shared__ float yt[128][16];
    __shared__ float ht[128][16];
    __shared__ float bbe[128], ble1[128];

    const int tid = threadIdx.x;
    {
        const float4* s1 = (const float4*)W_be;
        const float4* s2 = (const float4*)W_le1;   // rows 0..127 = W1a
        float4* d1 = (float4*)Wb;
        float4* d2 = (float4*)Wa;
        for (int i = tid; i < 4096; i += 256) { d1[i] = s1[i]; d2[i] = s2[i]; }
    }
    if (tid < 128) { bbe[tid] = b_be[tid]; ble1[tid] = b_le1[tid]; }

    const int bt0 = blockIdx.x * 16;
    {
        const float4* ys = (const float4*)(y + (size_t)bt0 * 128);
        for (int q = tid; q < 512; q += 256) {
            float4 v = ys[q];
            int r = q >> 5, n4 = (q & 31) * 4;
            yt[n4 + 0][r] = v.x; yt[n4 + 1][r] = v.y;
            yt[n4 + 2][r] = v.z; yt[n4 + 3][r] = v.w;
        }
    }
    __syncthreads();

    const int j = tid & 127, rh = tid >> 7;
    float acc[8];

    #pragma unroll
    for (int s = 0; s < 8; s++) acc[s] = bbe[j];
    #pragma unroll 4
    for (int k = 0; k < 128; k++) {
        float w = Wb[k * 128 + j];
        float4 a0 = *(const float4*)&yt[k][rh * 8];
        float4 a1 = *(const float4*)&yt[k][rh * 8 + 4];
        acc[0] += w * a0.x; acc[1] += w * a0.y; acc[2] += w * a0.z; acc[3] += w * a0.w;
        acc[4] += w * a1.x; acc[5] += w * a1.y; acc[6] += w * a1.z; acc[7] += w * a1.w;
    }
    #pragma unroll
    for (int s = 0; s < 8; s++) ht[j][rh * 8 + s] = tanhf(acc[s]);
    __syncthreads();

    #pragma unroll
    for (int s = 0; s < 8; s++) acc[s] = ble1[j];
    #pragma unroll 4
    for (int k = 0; k < 128; k++) {
        float w = Wa[k * 128 + j];
        float4 a0 = *(const float4*)&ht[k][rh * 8];
        float4 a1 = *(const float4*)&ht[k][rh * 8 + 4];
        acc[0] += w * a0.x; acc[1] += w * a0.y; acc[2] += w * a0.z; acc[3] += w * a0.w;
        acc[4] += w * a1.x; acc[5] += w * a1.y; acc[6] += w * a1.z; acc[7] += w * a1.w;
    }
    #pragma unroll
    for (int s = 0; s < 8; s++) {
        int r = rh * 8 + s;
        A[(size_t)(bt0 + r) * 128 + j] = acc[s];
    }
    if (rh == 0 && (bt0 & 255) == 0) {
        h0[(bt0 >> 8) * 128 + j] = ht[j][0];
    }
}

// ---------------------------------------------------------------------------
// Kernel B: initial step (t=0). Writes kl0 to slab 0, zeros slabs 1..31.
// ---------------------------------------------------------------------------
__global__ __launch_bounds__(128) void kB(
        const float* __restrict__ h0, const float* __restrict__ W_ic,
        const float* __restrict__ b_ic, const float* __restrict__ m_0,
        const float* __restrict__ log_Q_0, const float* __restrict__ eps0,
        float* __restrict__ zout, float* __restrict__ klw) {
    __shared__ float hr[128];
    __shared__ float mp[128];
    const int b = blockIdx.x, tid = threadIdx.x;
    hr[tid] = h0[b * 128 + tid];
    __syncthreads();
    float acc = b_ic[tid];
    #pragma unroll 8
    for (int k = 0; k < 128; k++) acc += hr[k] * W_ic[k * 128 + tid];
    mp[tid] = acc;
    __syncthreads();

    float term = 0.f;
    if (tid < 64) {
        float m = mp[tid];
        float P = softplus_f(mp[tid + 64]);
        float sq = sqrtf(P);
        #pragma unroll
        for (int s = 0; s < 8; s++) {
            float e = eps0[((size_t)s * B + b) * 64 + tid];
            zout[(((size_t)s * B + b) * T + 0) * 64 + tid] = m + sq * e;
        }
        float Q0 = softplus_f(log_Q_0[tid]);
        float d = m - m_0[tid];
        term = 0.5f * (logf(Q0) - logf(P) + (P + d * d) / Q0 - 1.f);
    }
    #pragma unroll
    for (int off = 32; off; off >>= 1) term += __shfl_down(term, off);
    if (tid == 0) klw[(size_t)b * T] = term;
    else if (tid < 32) klw[(size_t)tid * BT + (size_t)b * T] = 0.f;
}

// ---------------------------------------------------------------------------
// Kernel C (MFMA, NS=1): scan t=1..T-1.
// 1024 blocks = (b = bid>>3, s = bid&7); 256 threads = 4 waves.
// NO launch_bounds min-waves (R4 lesson: forcing 4 waves/EU made LLVM cap
// VGPR at 64 and spill the 64-VGPR weight fragments to scratch ->
// FETCH/WRITE +150MB, 3.3x slower). Occupancy comes from grid: VGPR~120
// -> 4 waves/SIMD -> 4 blocks/CU resident.
// Per-lane loop-invariant epilogue constants live in LDS (saves ~20 VGPR).
// ---------------------------------------------------------------------------
__global__ __launch_bounds__(256) void kC(
        const float* __restrict__ Aglob,
        const float* __restrict__ W_le1, const float* __restrict__ W_le2,
        const float* __restrict__ b_le2,
        const float* __restrict__ W_dyn1, const float* __restrict__ b_dyn1,
        const float* __restrict__ W_dyn2, const float* __restrict__ b_dyn2,
        const float* __restrict__ log_Q, const float* __restrict__ eps,
        float* __restrict__ zout, float* __restrict__ klw) {
    __shared__ alignas(16) _Float16 zSm[16][72];    // row 0 live, rows 1..15 zero
    __shared__ alignas(16) _Float16 hidS[16][136];
    __shared__ alignas(16) _Float16 gS[16][72];
    __shared__ alignas(16) float bmS[64], bpS[64], bmuS[64], bd1S[64], invQS[64];

    const int tid = threadIdx.x;
    const int b = blockIdx.x >> 3, s = blockIdx.x & 7;
    const int w = tid >> 6, l = tid & 63;
    const int lo = l & 15, hi = l >> 4;
    const int cg = 16 * w + 4 * hi;     // col base for dyn/m/P/mu/g
    const bool act = (lo == 0);

    // ---- zero f16 LDS (rows >=1 stay zero forever); fill const tables ----
    {
        _Float16* p1 = &zSm[0][0];
        _Float16* p2 = &hidS[0][0];
        _Float16* p3 = &gS[0][0];
        for (int i = tid; i < 16 * 72; i += 256) { p1[i] = (_Float16)0.f; p3[i] = (_Float16)0.f; }
        for (int i = tid; i < 16 * 136; i += 256) p2[i] = (_Float16)0.f;
    }
    if (tid < 64) {
        bmS[tid]   = b_le2[tid];
        bpS[tid]   = b_le2[64 + tid];
        bmuS[tid]  = b_dyn2[tid];
        bd1S[tid]  = b_dyn1[tid];
        invQS[tid] = 1.f / softplus_f(log_Q[tid]);
    }

    // ---- static weight fragments (64 VGPRs) ----
    f16x8_t a1[2][2], a2[2][4], a3[2], a4[2];
    #pragma unroll
    for (int ct = 0; ct < 2; ++ct)
        #pragma unroll
        for (int kt = 0; kt < 2; ++kt) {
            f16x8_t f;
            #pragma unroll
            for (int e = 0; e < 8; ++e)
                f[e] = (_Float16)W_le1[(size_t)(128 + kt * 32 + 8 * hi + e) * 128 + (32 * w + 16 * ct + lo)];
            a1[ct][kt] = f;
        }
    #pragma unroll
    for (int ct = 0; ct < 2; ++ct) {
        const int col = (ct == 0 ? 16 * w : 64 + 16 * w) + lo;
        #pragma unroll
        for (int kt = 0; kt < 4; ++kt) {
            f16x8_t f;
            #pragma unroll
            for (int e = 0; e < 8; ++e)
                f[e] = (_Float16)W_le2[(size_t)(kt * 32 + 8 * hi + e) * 128 + col];
            a2[ct][kt] = f;
        }
    }
    #pragma unroll
    for (int kt = 0; kt < 2; ++kt) {
        f16x8_t f, g;
        #pragma unroll
        for (int e = 0; e < 8; ++e) {
            f[e] = (_Float16)W_dyn1[(size_t)(kt * 32 + 8 * hi + e) * 64 + (16 * w + lo)];
            g[e] = (_Float16)W_dyn2[(size_t)(kt * 32 + 8 * hi + e) * 64 + (16 * w + lo)];
        }
        a3[kt] = f; a4[kt] = g;
    }

    // ---- pointers (active lanes) ----
    const float* ap = Aglob + ((size_t)b * T + 1) * 128 + 32 * w + 4 * hi;
    const float* ep = eps + ((size_t)s * B + b) * 64 + cg;               // t=1
    float*       zp = zout + (((size_t)s * B + b) * T + 1) * 64 + cg;
    float*       kp = klw + (size_t)(s * 4 + w) * BT + (size_t)b * T;

    __syncthreads();
    // ---- stage z0 ----
    if (tid < 64)
        zSm[0][tid] = (_Float16)zout[(((size_t)s * B + b) * T + 0) * 64 + tid];
    __syncthreads();

    // ---- software-pipelined prefetch (t=1) ----
    f32x4_t aN0 = {0,0,0,0}, aN1 = {0,0,0,0}, eN = {0,0,0,0};
    if (act) {
        aN0 = *(const f32x4_t*)ap;
        aN1 = *(const f32x4_t*)(ap + 16);
        eN  = *(const f32x4_t*)ep;
    }

    for (int t = 1; t < T; ++t) {
        const f32x4_t aC0 = aN0, aC1 = aN1, eC = eN;

        // ---- phase A MFMAs: z@W1b ; z@Wd1 ----
        const f16x8_t bz0 = *(const f16x8_t*)&zSm[lo][8 * hi];
        const f16x8_t bz1 = *(const f16x8_t*)&zSm[lo][32 + 8 * hi];

        f32x4_t acc1a = {0.f,0.f,0.f,0.f}, acc1b = {0.f,0.f,0.f,0.f}, acc3 = {0.f,0.f,0.f,0.f};
        acc1a = __builtin_amdgcn_mfma_f32_16x16x32_f16(a1[0][0], bz0, acc1a, 0, 0, 0);
        acc1b = __builtin_amdgcn_mfma_f32_16x16x32_f16(a1[1][0], bz0, acc1b, 0, 0, 0);
        acc3  = __builtin_amdgcn_mfma_f32_16x16x32_f16(a3[0],    bz0, acc3,  0, 0, 0);
        acc1a = __builtin_amdgcn_mfma_f32_16x16x32_f16(a1[0][1], bz1, acc1a, 0, 0, 0);
        acc1b = __builtin_amdgcn_mfma_f32_16x16x32_f16(a1[1][1], bz1, acc1b, 0, 0, 0);
        acc3  = __builtin_amdgcn_mfma_f32_16x16x32_f16(a3[1],    bz1, acc3,  0, 0, 0);

        // issue next-step global prefetch early (covered by ~1 full step)
        if (act && t < T - 1) {
            ap += 128; ep += (size_t)S * B * 64;
            aN0 = *(const f32x4_t*)ap;
            aN1 = *(const f32x4_t*)(ap + 16);
            eN  = *(const f32x4_t*)ep;
        }

        // ---- in-lane activation (producer lanes) ----
        if (act) {
            const f32x4_t bd1v = *(const f32x4_t*)&bd1S[cg];
            f16x4_t hv0, hv1, gv;
            #pragma unroll
            for (int r = 0; r < 4; ++r) {
                hv0[r] = (_Float16)fast_tanh(acc1a[r] + aC0[r]);
                hv1[r] = (_Float16)fast_tanh(acc1b[r] + aC1[r]);
                gv[r]  = (_Float16)fast_tanh(acc3[r] + bd1v[r]);
            }
            *(f16x4_t*)&hidS[0][32 * w + 4 * hi]      = hv0;
            *(f16x4_t*)&hidS[0][32 * w + 16 + 4 * hi] = hv1;
            *(f16x4_t*)&gS[0][cg]                     = gv;
        }
        __syncthreads();   // (1) hid/g visible

        // ---- phase B MFMAs: hid@W2 ; g@Wd2 ----
        const f16x8_t bh0 = *(const f16x8_t*)&hidS[lo][ 0 + 8 * hi];
        const f16x8_t bh1 = *(const f16x8_t*)&hidS[lo][32 + 8 * hi];
        const f16x8_t bh2 = *(const f16x8_t*)&hidS[lo][64 + 8 * hi];
        const f16x8_t bh3 = *(const f16x8_t*)&hidS[lo][96 + 8 * hi];
        const f16x8_t bg0 = *(const f16x8_t*)&gS[lo][8 * hi];
        const f16x8_t bg1 = *(const f16x8_t*)&gS[lo][32 + 8 * hi];

        f32x4_t accm = {0.f,0.f,0.f,0.f}, accp = {0.f,0.f,0.f,0.f}, acc4 = {0.f,0.f,0.f,0.f};
        accm = __builtin_amdgcn_mfma_f32_16x16x32_f16(a2[0][0], bh0, accm, 0, 0, 0);
        accp = __builtin_amdgcn_mfma_f32_16x16x32_f16(a2[1][0], bh0, accp, 0, 0, 0);
        acc4 = __builtin_amdgcn_mfma_f32_16x16x32_f16(a4[0],    bg0, acc4, 0, 0, 0);
        accm = __builtin_amdgcn_mfma_f32_16x16x32_f16(a2[0][1], bh1, accm, 0, 0, 0);
        accp = __builtin_amdgcn_mfma_f32_16x16x32_f16(a2[1][1], bh1, accp, 0, 0, 0);
        acc4 = __builtin_amdgcn_mfma_f32_16x16x32_f16(a4[1],    bg1, acc4, 0, 0, 0);
        accm = __builtin_amdgcn_mfma_f32_16x16x32_f16(a2[0][2], bh2, accm, 0, 0, 0);
        accp = __builtin_amdgcn_mfma_f32_16x16x32_f16(a2[1][2], bh2, accp, 0, 0, 0);
        accm = __builtin_amdgcn_mfma_f32_16x16x32_f16(a2[0][3], bh3, accm, 0, 0, 0);
        accp = __builtin_amdgcn_mfma_f32_16x16x32_f16(a2[1][3], bh3, accp, 0, 0, 0);

        // ---- in-lane epilogue (producer lanes) ----
        float term = 0.f;
        if (act) {
            const f32x4_t bm   = *(const f32x4_t*)&bmS[cg];
            const f32x4_t bp   = *(const f32x4_t*)&bpS[cg];
            const f32x4_t bmu  = *(const f32x4_t*)&bmuS[cg];
            const f32x4_t invQ = *(const f32x4_t*)&invQS[cg];
            f16x4_t zv;
            f32x4_t zst;
            #pragma unroll
            for (int r = 0; r < 4; ++r) {
                float m  = accm[r] + bm[r];
                float P  = softplus_fast(accp[r] + bp[r]);
                float mu = acc4[r] + bmu[r];
                float z  = m + sqrtf(P) * eC[r];
                zst[r] = z;
                zv[r]  = (_Float16)z;
                float d = m - mu;
                term += (P + d * d) * invQ[r] - __logf(P * invQ[r]) - 1.f;
            }
            *(f32x4_t*)zp = zst; zp += 64;
            *(f16x4_t*)&zSm[0][cg] = zv;
        }
        term += __shfl_down(term, 32);
        term += __shfl_down(term, 16);
        if (l == 0) kp[t] = 0.0625f * term;     // 0.5 * 1/8 * wave partial
        __syncthreads();   // (2) zSm visible for next step
    }
}

// ---------------------------------------------------------------------------
// Kernel P: projection + Poisson ell + m_stat.
// ---------------------------------------------------------------------------
__global__ __launch_bounds__(256) void kP(
        const float* __restrict__ zin, const float* __restrict__ C,
        const float* __restrict__ b_c, const float* __restrict__ y,
        float* __restrict__ m_stat, float* __restrict__ ell) {
    __shared__ float Cl[64 * 128];
    __shared__ float bc[128];
    __shared__ float ztl[64][8];
    __shared__ float red4[4];

    const int tid = threadIdx.x;
    {
        const float4* s = (const float4*)C;
        float4* d = (float4*)Cl;
        for (int i = tid; i < 2048; i += 256) d[i] = s[i];
    }
    if (tid < 128) bc[tid] = b_c[tid];

    const int bt0 = blockIdx.x * 8;
    const int n = tid & 127, shh = tid >> 7;

    for (int it = 0; it < 8; it++) {
        const int bt = bt0 + it;
        const int b = bt >> 8, t = bt & 255;
        __syncthreads();
        {
            int s_ = tid >> 6, l_ = tid & 63;
            ztl[l_][s_] = zin[(((size_t)s_ * B + b) * T + t) * 64 + l_];
            int i1 = tid + 256;
            s_ = i1 >> 6; l_ = i1 & 63;
            ztl[l_][s_] = zin[(((size_t)s_ * B + b) * T + t) * 64 + l_];
        }
        __syncthreads();
        if (tid < 64) {
            float4 a = *(const float4*)&ztl[tid][0];
            float4 bq = *(const float4*)&ztl[tid][4];
            m_stat[(size_t)bt * 64 + tid] =
                0.125f * (a.x + a.y + a.z + a.w + bq.x + bq.y + bq.z + bq.w);
        }
        float4 acc = {0.f, 0.f, 0.f, 0.f};
        #pragma unroll 4
        for (int k = 0; k < 64; k++) {
            float c = Cl[k * 128 + n];
            float4 z4 = *(const float4*)&ztl[k][shh * 4];
            acc.x += c * z4.x; acc.y += c * z4.y; acc.z += c * z4.z; acc.w += c * z4.w;
        }
        float bcv = bc[n];
        float yv = y[(size_t)bt * 128 + n];
        int yi = (int)yv;
        float ga = (yi < 2) ? 0.f
                 : ((yi == 2) ? 0.6931471805599453f
                 : ((yi == 3) ? 1.791759469228055f : 3.1780538303479458f));
        float term = 0.f;
        {
            float lr;
            lr = acc.x + bcv; term += yv * lr - __expf(lr) - ga;
            lr = acc.y + bcv; term += yv * lr - __expf(lr) - ga;
            lr = acc.z + bcv; term += yv * lr - __expf(lr) - ga;
            lr = acc.w + bcv; term += yv * lr - __expf(lr) - ga;
        }
        #pragma unroll
        for (int off = 32; off; off >>= 1) term += __shfl_down(term, off);
        if ((tid & 63) == 0) red4[tid >> 6] = term;
        __syncthreads();
        if (tid == 0) ell[bt] = 0.125f * (red4[0] + red4[1] + red4[2] + red4[3]);
    }
}

// ---------------------------------------------------------------------------
// Kernel R1/R2: two-stage loss reduction over 32 kl slabs + ell.
// ---------------------------------------------------------------------------
__global__ __launch_bounds__(256) void kR1(
        const float* __restrict__ klw, const float* __restrict__ ell,
        float* __restrict__ pw) {
    __shared__ float red4[4];
    const int tid = threadIdx.x;
    const int i0 = blockIdx.x * 512 + tid;
    float acc = 0.f;
    #pragma unroll
    for (int ii = 0; ii < 2; ii++) {
        int i = i0 + ii * 256;
        float v = -ell[i];
        #pragma unroll
        for (int sl = 0; sl < 32; sl++) v += klw[(size_t)sl * BT + i];
        acc += v;
    }
    #pragma unroll
    for (int off = 32; off; off >>= 1) acc += __shfl_down(acc, off);
    if ((tid & 63) == 0) red4[tid >> 6] = acc;
    __syncthreads();
    if (tid == 0) pw[blockIdx.x] = red4[0] + red4[1] + red4[2] + red4[3];
}

__global__ __launch_bounds__(64) void kR2(
        const float* __restrict__ pw, float* __restrict__ out0) {
    float v = pw[threadIdx.x];
    #pragma unroll
    for (int off = 32; off; off >>= 1) v += __shfl_down(v, off);
    if (threadIdx.x == 0) out0[0] = v * (1.0f / B);
}

// ---------------------------------------------------------------------------
extern "C" void kernel_launch(void* const* d_in, const int* in_sizes, int n_in,
                              void* d_out, int out_size, void* d_ws, size_t ws_size,
                              hipStream_t stream) {
    const float* y      = (const float*)d_in[0];
    const float* W_be   = (const float*)d_in[2];
    const float* b_be   = (const float*)d_in[3];
    const float* W_ic   = (const float*)d_in[4];
    const float* b_ic   = (const float*)d_in[5];
    const float* W_le1  = (const float*)d_in[6];
    const float* b_le1  = (const float*)d_in[7];
    const float* W_le2  = (const float*)d_in[8];
    const float* b_le2  = (const float*)d_in[9];
    const float* W_dyn1 = (const float*)d_in[10];
    const float* b_dyn1 = (const float*)d_in[11];
    const float* W_dyn2 = (const float*)d_in[12];
    const float* b_dyn2 = (const float*)d_in[13];
    const float* C      = (const float*)d_in[14];
    const float* b_c    = (const float*)d_in[15];
    const float* log_Q  = (const float*)d_in[16];
    const float* m_0    = (const float*)d_in[17];
    const float* log_Q_0= (const float*)d_in[18];
    const float* eps0   = (const float*)d_in[19];
    const float* eps    = (const float*)d_in[20];

    float* out = (float*)d_out;
    float* zo  = out + 1;
    float* ms  = out + 1 + (size_t)S * B * T * L;

    float* ws   = (float*)d_ws;
    float* klw  = ws;                                      // 32*B*T
    float* ellw = klw + (size_t)32 * BT;                   // B*T
    float* pw   = ellw + (size_t)BT;                       // 64
    float* h0   = pw + 64;                                 // B*128
    float* A    = h0 + (size_t)B * 128;                    // B*T*128

    kA<<<2048, 256, 0, stream>>>(y, W_be, b_be, W_le1, b_le1, A, h0);
    kB<<<128, 128, 0, stream>>>(h0, W_ic, b_ic, m_0, log_Q_0, eps0, zo, klw);
    kC<<<1024, 256, 0, stream>>>(A, W_le1, W_le2, b_le2, W_dyn1, b_dyn1,
                                 W_dyn2, b_dyn2, log_Q, eps, zo, klw);
    kP<<<4096, 256, 0, stream>>>(zo, C, b_c, y, ms, ellw);
    kR1<<<64, 256, 0, stream>>>(klw, ellw, pw);
    kR2<<<1, 64, 0, stream>>>(pw, out);
}

// Round 6
// 897.623 us; speedup vs baseline: 1.5429x; 1.4947x over previous
//
#include <hip/hip_runtime.h>

// Problem constants
constexpr int S = 8, B = 128, T = 256, N = 128;
constexpr int L = 64, Hh = 128, Hd = 64, Hl = 128;
constexpr int BT = B * T;

#define DEVFN __device__ __forceinline__

typedef float    f32x4_t __attribute__((ext_vector_type(4)));
typedef _Float16 f16x8_t __attribute__((ext_vector_type(8)));
typedef _Float16 f16x4_t __attribute__((ext_vector_type(4)));

DEVFN float softplus_f(float x) {            // accurate (prologue only)
    return (x > 0.f) ? (x + log1pf(expf(-x))) : log1pf(expf(x));
}
DEVFN float softplus_fast(float x) {         // branchless, native trans
    return fmaxf(x, 0.f) + __logf(1.f + __expf(-fabsf(x)));
}
DEVFN float fast_tanh(float x) {
    float ex = __builtin_exp2f(x * 2.885390081777927f);
    return 1.f - 2.f / (ex + 1.f);
}

// ---------------------------------------------------------------------------
// Kernel A: per (b,t) row:  h = tanh(y @ W_be + b_be);  A = h @ W1a + b_le1
// ---------------------------------------------------------------------------
__global__ __launch_bounds__(256) void kA(
        const float* __restrict__ y,
        const float* __restrict__ W_be, const float* __restrict__ b_be,
        const float* __restrict__ W_le1, const float* __restrict__ b_le1,
        float* __restrict__ A, float* __restrict__ h0) {
    __shared__ float Wb[128 * 128];
    __shared__ float Wa[128 * 128];
    __shared__ float yt[128][16];
    __shared__ float ht[128][16];
    __shared__ float bbe[128], ble1[128];

    const int tid = threadIdx.x;
    {
        const float4* s1 = (const float4*)W_be;
        const float4* s2 = (const float4*)W_le1;   // rows 0..127 = W1a
        float4* d1 = (float4*)Wb;
        float4* d2 = (float4*)Wa;
        for (int i = tid; i < 4096; i += 256) { d1[i] = s1[i]; d2[i] = s2[i]; }
    }
    if (tid < 128) { bbe[tid] = b_be[tid]; ble1[tid] = b_le1[tid]; }

    const int bt0 = blockIdx.x * 16;
    {
        const float4* ys = (const float4*)(y + (size_t)bt0 * 128);
        for (int q = tid; q < 512; q += 256) {
            float4 v = ys[q];
            int r = q >> 5, n4 = (q & 31) * 4;
            yt[n4 + 0][r] = v.x; yt[n4 + 1][r] = v.y;
            yt[n4 + 2][r] = v.z; yt[n4 + 3][r] = v.w;
        }
    }
    __syncthreads();

    const int j = tid & 127, rh = tid >> 7;
    float acc[8];

    #pragma unroll
    for (int s = 0; s < 8; s++) acc[s] = bbe[j];
    #pragma unroll 4
    for (int k = 0; k < 128; k++) {
        float w = Wb[k * 128 + j];
        float4 a0 = *(const float4*)&yt[k][rh * 8];
        float4 a1 = *(const float4*)&yt[k][rh * 8 + 4];
        acc[0] += w * a0.x; acc[1] += w * a0.y; acc[2] += w * a0.z; acc[3] += w * a0.w;
        acc[4] += w * a1.x; acc[5] += w * a1.y; acc[6] += w * a1.z; acc[7] += w * a1.w;
    }
    #pragma unroll
    for (int s = 0; s < 8; s++) ht[j][rh * 8 + s] = tanhf(acc[s]);
    __syncthreads();

    #pragma unroll
    for (int s = 0; s < 8; s++) acc[s] = ble1[j];
    #pragma unroll 4
    for (int k = 0; k < 128; k++) {
        float w = Wa[k * 128 + j];
        float4 a0 = *(const float4*)&ht[k][rh * 8];
        float4 a1 = *(const float4*)&ht[k][rh * 8 + 4];
        acc[0] += w * a0.x; acc[1] += w * a0.y; acc[2] += w * a0.z; acc[3] += w * a0.w;
        acc[4] += w * a1.x; acc[5] += w * a1.y; acc[6] += w * a1.z; acc[7] += w * a1.w;
    }
    #pragma unroll
    for (int s = 0; s < 8; s++) {
        int r = rh * 8 + s;
        A[(size_t)(bt0 + r) * 128 + j] = acc[s];
    }
    if (rh == 0 && (bt0 & 255) == 0) {
        h0[(bt0 >> 8) * 128 + j] = ht[j][0];
    }
}

// ---------------------------------------------------------------------------
// Kernel B: initial step (t=0). Writes kl0 to slab 0, zeros slabs 1..31.
// ---------------------------------------------------------------------------
__global__ __launch_bounds__(128) void kB(
        const float* __restrict__ h0, const float* __restrict__ W_ic,
        const float* __restrict__ b_ic, const float* __restrict__ m_0,
        const float* __restrict__ log_Q_0, const float* __restrict__ eps0,
        float* __restrict__ zout, float* __restrict__ klw) {
    __shared__ float hr[128];
    __shared__ float mp[128];
    const int b = blockIdx.x, tid = threadIdx.x;
    hr[tid] = h0[b * 128 + tid];
    __syncthreads();
    float acc = b_ic[tid];
    #pragma unroll 8
    for (int k = 0; k < 128; k++) acc += hr[k] * W_ic[k * 128 + tid];
    mp[tid] = acc;
    __syncthreads();

    float term = 0.f;
    if (tid < 64) {
        float m = mp[tid];
        float P = softplus_f(mp[tid + 64]);
        float sq = sqrtf(P);
        #pragma unroll
        for (int s = 0; s < 8; s++) {
            float e = eps0[((size_t)s * B + b) * 64 + tid];
            zout[(((size_t)s * B + b) * T + 0) * 64 + tid] = m + sq * e;
        }
        float Q0 = softplus_f(log_Q_0[tid]);
        float d = m - m_0[tid];
        term = 0.5f * (logf(Q0) - logf(P) + (P + d * d) / Q0 - 1.f);
    }
    #pragma unroll
    for (int off = 32; off; off >>= 1) term += __shfl_down(term, off);
    if (tid == 0) klw[(size_t)b * T] = term;
    else if (tid < 32) klw[(size_t)tid * BT + (size_t)b * T] = 0.f;
}

// ---------------------------------------------------------------------------
// Kernel C (MFMA, NS=1, DENSE epilogue, 2 barriers/step): scan t=1..T-1.
// 1024 blocks = (b = bid>>3, s = bid&7); 256 threads = 4 waves.
// MFMA convention (verified R2+): lane l: lo=l&15, hi=l>>4;
//   A[row=lo][k=8hi+e], B[k=8hi+e][col=lo]; D: col=lo, row=4hi+reg.
// Key structure (R3/R5 lessons):
//  - DENSE activation/epilogue: f32 accs staged via wave-private LDS slots;
//    all lanes share tanh/softplus work (in-lane masked epilogue was 3x
//    slower: wave64 issue cost doesn't shrink with exec mask).
//  - Staging slots are WAVE-PRIVATE -> no __syncthreads between producer
//    write and consumer read (LDS ops of one wave are in-order); only 2
//    cross-wave barriers per step (hidS/gS, zSm).
//  - NO launch_bounds min-waves (R4: forced 64-VGPR cap -> spill).
// ---------------------------------------------------------------------------
__global__ __launch_bounds__(256) void kC(
        const float* __restrict__ Aglob,
        const float* __restrict__ W_le1, const float* __restrict__ W_le2,
        const float* __restrict__ b_le2,
        const float* __restrict__ W_dyn1, const float* __restrict__ b_dyn1,
        const float* __restrict__ W_dyn2, const float* __restrict__ b_dyn2,
        const float* __restrict__ log_Q, const float* __restrict__ eps,
        float* __restrict__ zout, float* __restrict__ klw) {
    __shared__ alignas(16) _Float16 zSm[16][72];    // row 0 live, rows 1..15 zero
    __shared__ alignas(16) _Float16 hidS[16][136];
    __shared__ alignas(16) _Float16 gS[16][72];
    __shared__ alignas(16) float stH[136];          // phase-A acc staging (f32)
    __shared__ alignas(16) float stG[72];
    __shared__ alignas(16) float stM[136];          // phase-B acc staging
    __shared__ alignas(16) float stMU[72];
    __shared__ float bmS[64], bpS[64], bmuS[64], bd1S[64], invQS[64];
    __shared__ float red[4];

    const int tid = threadIdx.x;
    const int b = blockIdx.x >> 3, s = blockIdx.x & 7;
    const int w = tid >> 6, l = tid & 63;
    const int lo = l & 15, hi = l >> 4;
    const bool prod = (lo == 0);        // producer lanes (valid D col 0)

    // ---- zero f16 LDS (rows >=1 stay zero forever); fill const tables ----
    {
        _Float16* p1 = &zSm[0][0];
        _Float16* p2 = &hidS[0][0];
        _Float16* p3 = &gS[0][0];
        for (int i = tid; i < 16 * 72; i += 256) { p1[i] = (_Float16)0.f; p3[i] = (_Float16)0.f; }
        for (int i = tid; i < 16 * 136; i += 256) p2[i] = (_Float16)0.f;
    }
    if (tid < 64) {
        bmS[tid]   = b_le2[tid];
        bpS[tid]   = b_le2[64 + tid];
        bmuS[tid]  = b_dyn2[tid];
        bd1S[tid]  = b_dyn1[tid];
        invQS[tid] = 1.f / softplus_f(log_Q[tid]);
    }

    // ---- static weight fragments (64 VGPRs) ----
    f16x8_t a1[2][2], a2[2][4], a3[2], a4[2];
    #pragma unroll
    for (int ct = 0; ct < 2; ++ct)
        #pragma unroll
        for (int kt = 0; kt < 2; ++kt) {
            f16x8_t f;
            #pragma unroll
            for (int e = 0; e < 8; ++e)
                f[e] = (_Float16)W_le1[(size_t)(128 + kt * 32 + 8 * hi + e) * 128 + (32 * w + 16 * ct + lo)];
            a1[ct][kt] = f;
        }
    #pragma unroll
    for (int ct = 0; ct < 2; ++ct) {
        const int col = (ct == 0 ? 16 * w : 64 + 16 * w) + lo;
        #pragma unroll
        for (int kt = 0; kt < 4; ++kt) {
            f16x8_t f;
            #pragma unroll
            for (int e = 0; e < 8; ++e)
                f[e] = (_Float16)W_le2[(size_t)(kt * 32 + 8 * hi + e) * 128 + col];
            a2[ct][kt] = f;
        }
    }
    #pragma unroll
    for (int kt = 0; kt < 2; ++kt) {
        f16x8_t f, g;
        #pragma unroll
        for (int e = 0; e < 8; ++e) {
            f[e] = (_Float16)W_dyn1[(size_t)(kt * 32 + 8 * hi + e) * 64 + (16 * w + lo)];
            g[e] = (_Float16)W_dyn2[(size_t)(kt * 32 + 8 * hi + e) * 64 + (16 * w + lo)];
        }
        a3[kt] = f; a4[kt] = g;
    }

    // ---- dense-role pointers ----
    // act lanes (l<32): hid col = 32w+l ; eps/epi lanes (l<16): col = 16w+l
    const int hcol = 32 * w + l;              // valid when l<32
    const int ecol = 16 * w + l;              // valid when l<16
    const float* ap = Aglob + ((size_t)b * T + 1) * 128 + hcol;
    const float* ep = eps + ((size_t)s * B + b) * 64 + ecol;             // t=1
    float*       zp = zout + (((size_t)s * B + b) * T + 1) * 64 + ecol;
    float*       kp = klw + (size_t)(s * 4 + w) * BT + (size_t)b * T;

    __syncthreads();
    // ---- stage z0 ----
    if (tid < 64)
        zSm[0][tid] = (_Float16)zout[(((size_t)s * B + b) * T + 0) * 64 + tid];
    __syncthreads();

    // ---- software-pipelined prefetch (t=1) ----
    float aN = 0.f, eN = 0.f;
    if (l < 32) aN = *ap;
    if (l < 16) eN = *ep;

    for (int t = 1; t < T; ++t) {
        const float aC = aN, eC = eN;

        // off-chain: store previous step's KL (red[] from prev epi; safe:
        // next red writes happen only after barrier (2) below)
        if (tid == 0 && t > 1) kp[t - 1] = 0.0625f * (red[0] + red[1] + red[2] + red[3]);

        // next-step global prefetch (consumed next iteration)
        if (t < T - 1) {
            if (l < 32) { ap += 128; aN = *ap; }
            if (l < 16) { ep += (size_t)S * B * 64; eN = *ep; }
        }

        // ---- phase A MFMAs: z@W1b ; z@Wd1 ----
        const f16x8_t bz0 = *(const f16x8_t*)&zSm[lo][8 * hi];
        const f16x8_t bz1 = *(const f16x8_t*)&zSm[lo][32 + 8 * hi];

        f32x4_t acc1a = {0.f,0.f,0.f,0.f}, acc1b = {0.f,0.f,0.f,0.f}, acc3 = {0.f,0.f,0.f,0.f};
        acc1a = __builtin_amdgcn_mfma_f32_16x16x32_f16(a1[0][0], bz0, acc1a, 0, 0, 0);
        acc1b = __builtin_amdgcn_mfma_f32_16x16x32_f16(a1[1][0], bz0, acc1b, 0, 0, 0);
        acc3  = __builtin_amdgcn_mfma_f32_16x16x32_f16(a3[0],    bz0, acc3,  0, 0, 0);
        acc1a = __builtin_amdgcn_mfma_f32_16x16x32_f16(a1[0][1], bz1, acc1a, 0, 0, 0);
        acc1b = __builtin_amdgcn_mfma_f32_16x16x32_f16(a1[1][1], bz1, acc1b, 0, 0, 0);
        acc3  = __builtin_amdgcn_mfma_f32_16x16x32_f16(a3[1],    bz1, acc3,  0, 0, 0);

        // wave-private staging (no barrier needed: same-wave LDS in-order)
        if (prod) {
            *(f32x4_t*)&stH[32 * w + 4 * hi]      = acc1a;
            *(f32x4_t*)&stH[32 * w + 16 + 4 * hi] = acc1b;
            *(f32x4_t*)&stG[16 * w + 4 * hi]      = acc3;
        }
        asm volatile("" ::: "memory");

        // ---- dense activation (same-wave consumers) ----
        if (l < 32) {
            hidS[0][hcol] = (_Float16)fast_tanh(stH[hcol] + aC);
        } else if (l < 48) {
            int c = 16 * w + (l - 32);
            gS[0][c] = (_Float16)fast_tanh(stG[c] + bd1S[c]);
        }
        __syncthreads();   // (1) hid/g visible cross-wave

        // ---- phase B MFMAs: hid@W2 ; g@Wd2 ----
        const f16x8_t bh0 = *(const f16x8_t*)&hidS[lo][ 0 + 8 * hi];
        const f16x8_t bh1 = *(const f16x8_t*)&hidS[lo][32 + 8 * hi];
        const f16x8_t bh2 = *(const f16x8_t*)&hidS[lo][64 + 8 * hi];
        const f16x8_t bh3 = *(const f16x8_t*)&hidS[lo][96 + 8 * hi];
        const f16x8_t bg0 = *(const f16x8_t*)&gS[lo][8 * hi];
        const f16x8_t bg1 = *(const f16x8_t*)&gS[lo][32 + 8 * hi];

        f32x4_t accm = {0.f,0.f,0.f,0.f}, accp = {0.f,0.f,0.f,0.f}, acc4 = {0.f,0.f,0.f,0.f};
        accm = __builtin_amdgcn_mfma_f32_16x16x32_f16(a2[0][0], bh0, accm, 0, 0, 0);
        accp = __builtin_amdgcn_mfma_f32_16x16x32_f16(a2[1][0], bh0, accp, 0, 0, 0);
        acc4 = __builtin_amdgcn_mfma_f32_16x16x32_f16(a4[0],    bg0, acc4, 0, 0, 0);
        accm = __builtin_amdgcn_mfma_f32_16x16x32_f16(a2[0][1], bh1, accm, 0, 0, 0);
        accp = __builtin_amdgcn_mfma_f32_16x16x32_f16(a2[1][1], bh1, accp, 0, 0, 0);
        acc4 = __builtin_amdgcn_mfma_f32_16x16x32_f16(a4[1],    bg1, acc4, 0, 0, 0);
        accm = __builtin_amdgcn_mfma_f32_16x16x32_f16(a2[0][2], bh2, accm, 0, 0, 0);
        accp = __builtin_amdgcn_mfma_f32_16x16x32_f16(a2[1][2], bh2, accp, 0, 0, 0);
        accm = __builtin_amdgcn_mfma_f32_16x16x32_f16(a2[0][3], bh3, accm, 0, 0, 0);
        accp = __builtin_amdgcn_mfma_f32_16x16x32_f16(a2[1][3], bh3, accp, 0, 0, 0);

        if (prod) {
            *(f32x4_t*)&stM[16 * w + 4 * hi]       = accm;
            *(f32x4_t*)&stM[64 + 16 * w + 4 * hi]  = accp;
            *(f32x4_t*)&stMU[16 * w + 4 * hi]      = acc4;
        }
        asm volatile("" ::: "memory");

        // ---- dense epilogue (same-wave consumers, l<16) ----
        float term = 0.f;
        if (l < 16) {
            float m  = stM[ecol] + bmS[ecol];
            float P  = softplus_fast(stM[64 + ecol] + bpS[ecol]);
            float mu = stMU[ecol] + bmuS[ecol];
            float iq = invQS[ecol];
            float z  = m + sqrtf(P) * eC;
            *zp = z; zp += 64;
            zSm[0][ecol] = (_Float16)z;
            float d = m - mu;
            term = (P + d * d) * iq - __logf(P * iq) - 1.f;
        }
        term += __shfl_down(term, 8);
        term += __shfl_down(term, 4);
        term += __shfl_down(term, 2);
        term += __shfl_down(term, 1);
        if (l == 0) red[w] = term;
        __syncthreads();   // (2) zSm / red visible for next step
    }
    if (tid == 0) kp[T - 1] = 0.0625f * (red[0] + red[1] + red[2] + red[3]);
}

// ---------------------------------------------------------------------------
// Kernel P: projection + Poisson ell + m_stat.
// ---------------------------------------------------------------------------
__global__ __launch_bounds__(256) void kP(
        const float* __restrict__ zin, const float* __restrict__ C,
        const float* __restrict__ b_c, const float* __restrict__ y,
        float* __restrict__ m_stat, float* __restrict__ ell) {
    __shared__ float Cl[64 * 128];
    __shared__ float bc[128];
    __shared__ float ztl[64][8];
    __shared__ float red4[4];

    const int tid = threadIdx.x;
    {
        const float4* s = (const float4*)C;
        float4* d = (float4*)Cl;
        for (int i = tid; i < 2048; i += 256) d[i] = s[i];
    }
    if (tid < 128) bc[tid] = b_c[tid];

    const int bt0 = blockIdx.x * 8;
    const int n = tid & 127, shh = tid >> 7;

    for (int it = 0; it < 8; it++) {
        const int bt = bt0 + it;
        const int b = bt >> 8, t = bt & 255;
        __syncthreads();
        {
            int s_ = tid >> 6, l_ = tid & 63;
            ztl[l_][s_] = zin[(((size_t)s_ * B + b) * T + t) * 64 + l_];
            int i1 = tid + 256;
            s_ = i1 >> 6; l_ = i1 & 63;
            ztl[l_][s_] = zin[(((size_t)s_ * B + b) * T + t) * 64 + l_];
        }
        __syncthreads();
        if (tid < 64) {
            float4 a = *(const float4*)&ztl[tid][0];
            float4 bq = *(const float4*)&ztl[tid][4];
            m_stat[(size_t)bt * 64 + tid] =
                0.125f * (a.x + a.y + a.z + a.w + bq.x + bq.y + bq.z + bq.w);
        }
        float4 acc = {0.f, 0.f, 0.f, 0.f};
        #pragma unroll 4
        for (int k = 0; k < 64; k++) {
            float c = Cl[k * 128 + n];
            float4 z4 = *(const float4*)&ztl[k][shh * 4];
            acc.x += c * z4.x; acc.y += c * z4.y; acc.z += c * z4.z; acc.w += c * z4.w;
        }
        float bcv = bc[n];
        float yv = y[(size_t)bt * 128 + n];
        int yi = (int)yv;
        float ga = (yi < 2) ? 0.f
                 : ((yi == 2) ? 0.6931471805599453f
                 : ((yi == 3) ? 1.791759469228055f : 3.1780538303479458f));
        float term = 0.f;
        {
            float lr;
            lr = acc.x + bcv; term += yv * lr - __expf(lr) - ga;
            lr = acc.y + bcv; term += yv * lr - __expf(lr) - ga;
            lr = acc.z + bcv; term += yv * lr - __expf(lr) - ga;
            lr = acc.w + bcv; term += yv * lr - __expf(lr) - ga;
        }
        #pragma unroll
        for (int off = 32; off; off >>= 1) term += __shfl_down(term, off);
        if ((tid & 63) == 0) red4[tid >> 6] = term;
        __syncthreads();
        if (tid == 0) ell[bt] = 0.125f * (red4[0] + red4[1] + red4[2] + red4[3]);
    }
}

// ---------------------------------------------------------------------------
// Kernel R1/R2: two-stage loss reduction over 32 kl slabs + ell.
// ---------------------------------------------------------------------------
__global__ __launch_bounds__(256) void kR1(
        const float* __restrict__ klw, const float* __restrict__ ell,
        float* __restrict__ pw) {
    __shared__ float red4[4];
    const int tid = threadIdx.x;
    const int i0 = blockIdx.x * 512 + tid;
    float acc = 0.f;
    #pragma unroll
    for (int ii = 0; ii < 2; ii++) {
        int i = i0 + ii * 256;
        float v = -ell[i];
        #pragma unroll
        for (int sl = 0; sl < 32; sl++) v += klw[(size_t)sl * BT + i];
        acc += v;
    }
    #pragma unroll
    for (int off = 32; off; off >>= 1) acc += __shfl_down(acc, off);
    if ((tid & 63) == 0) red4[tid >> 6] = acc;
    __syncthreads();
    if (tid == 0) pw[blockIdx.x] = red4[0] + red4[1] + red4[2] + red4[3];
}

__global__ __launch_bounds__(64) void kR2(
        const float* __restrict__ pw, float* __restrict__ out0) {
    float v = pw[threadIdx.x];
    #pragma unroll
    for (int off = 32; off; off >>= 1) v += __shfl_down(v, off);
    if (threadIdx.x == 0) out0[0] = v * (1.0f / B);
}

// ---------------------------------------------------------------------------
extern "C" void kernel_launch(void* const* d_in, const int* in_sizes, int n_in,
                              void* d_out, int out_size, void* d_ws, size_t ws_size,
                              hipStream_t stream) {
    const float* y      = (const float*)d_in[0];
    const float* W_be   = (const float*)d_in[2];
    const float* b_be   = (const float*)d_in[3];
    const float* W_ic   = (const float*)d_in[4];
    const float* b_ic   = (const float*)d_in[5];
    const float* W_le1  = (const float*)d_in[6];
    const float* b_le1  = (const float*)d_in[7];
    const float* W_le2  = (const float*)d_in[8];
    const float* b_le2  = (const float*)d_in[9];
    const float* W_dyn1 = (const float*)d_in[10];
    const float* b_dyn1 = (const float*)d_in[11];
    const float* W_dyn2 = (const float*)d_in[12];
    const float* b_dyn2 = (const float*)d_in[13];
    const float* C      = (const float*)d_in[14];
    const float* b_c    = (const float*)d_in[15];
    const float* log_Q  = (const float*)d_in[16];
    const float* m_0    = (const float*)d_in[17];
    const float* log_Q_0= (const float*)d_in[18];
    const float* eps0   = (const float*)d_in[19];
    const float* eps    = (const float*)d_in[20];

    float* out = (float*)d_out;
    float* zo  = out + 1;
    float* ms  = out + 1 + (size_t)S * B * T * L;

    float* ws   = (float*)d_ws;
    float* klw  = ws;                                      // 32*B*T
    float* ellw = klw + (size_t)32 * BT;                   // B*T
    float* pw   = ellw + (size_t)BT;                       // 64
    float* h0   = pw + 64;                                 // B*128
    float* A    = h0 + (size_t)B * 128;                    // B*T*128

    kA<<<2048, 256, 0, stream>>>(y, W_be, b_be, W_le1, b_le1, A, h0);
    kB<<<128, 128, 0, stream>>>(h0, W_ic, b_ic, m_0, log_Q_0, eps0, zo, klw);
    kC<<<1024, 256, 0, stream>>>(A, W_le1, W_le2, b_le2, W_dyn1, b_dyn1,
                                 W_dyn2, b_dyn2, log_Q, eps, zo, klw);
    kP<<<4096, 256, 0, stream>>>(zo, C, b_c, y, ms, ellw);
    kR1<<<64, 256, 0, stream>>>(klw, ellw, pw);
    kR2<<<1, 64, 0, stream>>>(pw, out);
}

// Round 7
// 606.004 us; speedup vs baseline: 2.2853x; 1.4812x over previous
//
#include <hip/hip_runtime.h>

// Problem constants
constexpr int S = 8, B = 128, T = 256, N = 128;
constexpr int L = 64, Hh = 128, Hd = 64, Hl = 128;
constexpr int BT = B * T;

#define DEVFN __device__ __forceinline__

typedef float    f32x4_t __attribute__((ext_vector_type(4)));
typedef _Float16 f16x8_t __attribute__((ext_vector_type(8)));
typedef _Float16 f16x4_t __attribute__((ext_vector_type(4)));

DEVFN float softplus_f(float x) {            // accurate (prologue only)
    return (x > 0.f) ? (x + log1pf(expf(-x))) : log1pf(expf(x));
}
DEVFN float softplus_fast(float x) {         // branchless, native trans
    return fmaxf(x, 0.f) + __logf(1.f + __expf(-fabsf(x)));
}
DEVFN float fast_tanh(float x) {
    float ex = __builtin_exp2f(x * 2.885390081777927f);
    return 1.f - 2.f / (ex + 1.f);
}

// ---------------------------------------------------------------------------
// Kernel A: per (b,t) row:  h = tanh(y @ W_be + b_be);  A = h @ W1a + b_le1
// ---------------------------------------------------------------------------
__global__ __launch_bounds__(256) void kA(
        const float* __restrict__ y,
        const float* __restrict__ W_be, const float* __restrict__ b_be,
        const float* __restrict__ W_le1, const float* __restrict__ b_le1,
        float* __restrict__ A, float* __restrict__ h0) {
    __shared__ float Wb[128 * 128];
    __shared__ float Wa[128 * 128];
    __shared__ float yt[128][16];
    __shared__ float ht[128][16];
    __shared__ float bbe[128], ble1[128];

    const int tid = threadIdx.x;
    {
        const float4* s1 = (const float4*)W_be;
        const float4* s2 = (const float4*)W_le1;   // rows 0..127 = W1a
        float4* d1 = (float4*)Wb;
        float4* d2 = (float4*)Wa;
        for (int i = tid; i < 4096; i += 256) { d1[i] = s1[i]; d2[i] = s2[i]; }
    }
    if (tid < 128) { bbe[tid] = b_be[tid]; ble1[tid] = b_le1[tid]; }

    const int bt0 = blockIdx.x * 16;
    {
        const float4* ys = (const float4*)(y + (size_t)bt0 * 128);
        for (int q = tid; q < 512; q += 256) {
            float4 v = ys[q];
            int r = q >> 5, n4 = (q & 31) * 4;
            yt[n4 + 0][r] = v.x; yt[n4 + 1][r] = v.y;
            yt[n4 + 2][r] = v.z; yt[n4 + 3][r] = v.w;
        }
    }
    __syncthreads();

    const int j = tid & 127, rh = tid >> 7;
    float acc[8];

    #pragma unroll
    for (int s = 0; s < 8; s++) acc[s] = bbe[j];
    #pragma unroll 4
    for (int k = 0; k < 128; k++) {
        float w = Wb[k * 128 + j];
        float4 a0 = *(const float4*)&yt[k][rh * 8];
        float4 a1 = *(const float4*)&yt[k][rh * 8 + 4];
        acc[0] += w * a0.x; acc[1] += w * a0.y; acc[2] += w * a0.z; acc[3] += w * a0.w;
        acc[4] += w * a1.x; acc[5] += w * a1.y; acc[6] += w * a1.z; acc[7] += w * a1.w;
    }
    #pragma unroll
    for (int s = 0; s < 8; s++) ht[j][rh * 8 + s] = tanhf(acc[s]);
    __syncthreads();

    #pragma unroll
    for (int s = 0; s < 8; s++) acc[s] = ble1[j];
    #pragma unroll 4
    for (int k = 0; k < 128; k++) {
        float w = Wa[k * 128 + j];
        float4 a0 = *(const float4*)&ht[k][rh * 8];
        float4 a1 = *(const float4*)&ht[k][rh * 8 + 4];
        acc[0] += w * a0.x; acc[1] += w * a0.y; acc[2] += w * a0.z; acc[3] += w * a0.w;
        acc[4] += w * a1.x; acc[5] += w * a1.y; acc[6] += w * a1.z; acc[7] += w * a1.w;
    }
    #pragma unroll
    for (int s = 0; s < 8; s++) {
        int r = rh * 8 + s;
        A[(size_t)(bt0 + r) * 128 + j] = acc[s];
    }
    if (rh == 0 && (bt0 & 255) == 0) {
        h0[(bt0 >> 8) * 128 + j] = ht[j][0];
    }
}

// ---------------------------------------------------------------------------
// Kernel B: initial step (t=0). Writes kl0 to slab 0, zeros slabs 1..15.
// ---------------------------------------------------------------------------
__global__ __launch_bounds__(128) void kB(
        const float* __restrict__ h0, const float* __restrict__ W_ic,
        const float* __restrict__ b_ic, const float* __restrict__ m_0,
        const float* __restrict__ log_Q_0, const float* __restrict__ eps0,
        float* __restrict__ zout, float* __restrict__ klw) {
    __shared__ float hr[128];
    __shared__ float mp[128];
    const int b = blockIdx.x, tid = threadIdx.x;
    hr[tid] = h0[b * 128 + tid];
    __syncthreads();
    float acc = b_ic[tid];
    #pragma unroll 8
    for (int k = 0; k < 128; k++) acc += hr[k] * W_ic[k * 128 + tid];
    mp[tid] = acc;
    __syncthreads();

    float term = 0.f;
    if (tid < 64) {
        float m = mp[tid];
        float P = softplus_f(mp[tid + 64]);
        float sq = sqrtf(P);
        #pragma unroll
        for (int s = 0; s < 8; s++) {
            float e = eps0[((size_t)s * B + b) * 64 + tid];
            zout[(((size_t)s * B + b) * T + 0) * 64 + tid] = m + sq * e;
        }
        float Q0 = softplus_f(log_Q_0[tid]);
        float d = m - m_0[tid];
        term = 0.5f * (logf(Q0) - logf(P) + (P + d * d) / Q0 - 1.f);
    }
    #pragma unroll
    for (int off = 32; off; off >>= 1) term += __shfl_down(term, off);
    if (tid == 0) klw[(size_t)b * T] = term;
    else if (tid < 16) klw[(size_t)tid * BT + (size_t)b * T] = 0.f;
}

// ---------------------------------------------------------------------------
// Kernel C (MFMA, NS=2, wave-local staging, 2 barriers/step): scan t=1..T-1.
// 512 blocks = (b = bid>>2, sq = bid&3 -> samples 2sq,2sq+1); 4 waves.
// MFMA convention (verified R2+): lane l: lo=l&15, hi=l>>4;
//   A[row=lo][k=8hi+e], B[k=8hi+e][col=lo]; D: col=lo(sample), row=4hi+reg.
// Lessons baked in:
//  - NS=2: residency caps at ~2 blocks/CU regardless of grid (R3/R6 both
//    22%), so amortize fixed costs over 2 samples; 512 blocks = capacity.
//  - Dense activation/epilogue (R3/R6): wave64 issue cost doesn't shrink
//    with exec mask -> all lanes share scalar work.
//  - Wave-LOCAL staging (R6): wave w consumes exactly what it produced ->
//    no barrier between MFMA staging and activation/epilogue; 2 barriers.
//  - NO launch_bounds min-waves (R4 spill lesson).
// ---------------------------------------------------------------------------
__global__ __launch_bounds__(256) void kC(
        const float* __restrict__ Aglob,
        const float* __restrict__ W_le1, const float* __restrict__ W_le2,
        const float* __restrict__ b_le2,
        const float* __restrict__ W_dyn1, const float* __restrict__ b_dyn1,
        const float* __restrict__ W_dyn2, const float* __restrict__ b_dyn2,
        const float* __restrict__ log_Q, const float* __restrict__ eps,
        float* __restrict__ zout, float* __restrict__ klw) {
    __shared__ alignas(16) _Float16 zSm[16][72];    // rows 0,1 live; 2..15 zero
    __shared__ alignas(16) _Float16 hidS[16][136];
    __shared__ alignas(16) _Float16 gS[16][72];
    __shared__ alignas(16) float stH[2][136];       // phase-A acc staging (f32)
    __shared__ alignas(16) float stG[2][72];
    __shared__ alignas(16) float stM[2][136];       // phase-B acc staging
    __shared__ alignas(16) float stMU[2][72];
    __shared__ float bmS[64], bpS[64], bmuS[64], bd1S[64], invQS[64];
    __shared__ float red[4];

    const int tid = threadIdx.x;
    const int b = blockIdx.x >> 2, sq = blockIdx.x & 3, s0 = sq * 2;
    const int w = tid >> 6, l = tid & 63;
    const int lo = l & 15, hi = l >> 4;
    const bool prod = (lo < 2);         // producer lanes (valid D cols 0,1)

    // ---- zero f16 LDS (rows >=2 stay zero forever); fill const tables ----
    {
        _Float16* p1 = &zSm[0][0];
        _Float16* p2 = &hidS[0][0];
        _Float16* p3 = &gS[0][0];
        for (int i = tid; i < 16 * 72; i += 256) { p1[i] = (_Float16)0.f; p3[i] = (_Float16)0.f; }
        for (int i = tid; i < 16 * 136; i += 256) p2[i] = (_Float16)0.f;
    }
    if (tid < 64) {
        bmS[tid]   = b_le2[tid];
        bpS[tid]   = b_le2[64 + tid];
        bmuS[tid]  = b_dyn2[tid];
        bd1S[tid]  = b_dyn1[tid];
        invQS[tid] = 1.f / softplus_f(log_Q[tid]);
    }

    // ---- static weight fragments (64 VGPRs) ----
    f16x8_t a1[2][2], a2[2][4], a3[2], a4[2];
    #pragma unroll
    for (int ct = 0; ct < 2; ++ct)
        #pragma unroll
        for (int kt = 0; kt < 2; ++kt) {
            f16x8_t f;
            #pragma unroll
            for (int e = 0; e < 8; ++e)
                f[e] = (_Float16)W_le1[(size_t)(128 + kt * 32 + 8 * hi + e) * 128 + (32 * w + 16 * ct + lo)];
            a1[ct][kt] = f;
        }
    #pragma unroll
    for (int ct = 0; ct < 2; ++ct) {
        const int col = (ct == 0 ? 16 * w : 64 + 16 * w) + lo;
        #pragma unroll
        for (int kt = 0; kt < 4; ++kt) {
            f16x8_t f;
            #pragma unroll
            for (int e = 0; e < 8; ++e)
                f[e] = (_Float16)W_le2[(size_t)(kt * 32 + 8 * hi + e) * 128 + col];
            a2[ct][kt] = f;
        }
    }
    #pragma unroll
    for (int kt = 0; kt < 2; ++kt) {
        f16x8_t f, g;
        #pragma unroll
        for (int e = 0; e < 8; ++e) {
            f[e] = (_Float16)W_dyn1[(size_t)(kt * 32 + 8 * hi + e) * 64 + (16 * w + lo)];
            g[e] = (_Float16)W_dyn2[(size_t)(kt * 32 + 8 * hi + e) * 64 + (16 * w + lo)];
        }
        a3[kt] = f; a4[kt] = g;
    }

    // ---- dense wave-local role mappings ----
    // activation (hid): all 64 lanes: sample ha = l>>5, col hc = 32w + (l&31)
    // activation (g):   lanes l<32:  sample ga = l>>4, col gc = 16w + (l&15)
    // epilogue:         lanes l<32:  sample es = l>>4, col ec = 16w + (l&15)
    const int ha = l >> 5, hc = 32 * w + (l & 31);
    const int ga = (l >> 4) & 1, gc = 16 * w + (l & 15);
    const int es = ga, ec = gc;
    const float* ap = Aglob + ((size_t)b * T + 1) * 128 + hc;
    const float* ep = eps + (((size_t)(s0 + es)) * B + b) * 64 + ec;     // t=1
    float*       zp = zout + ((((size_t)(s0 + es)) * B + b) * T + 1) * 64 + ec;
    float*       kp = klw + (size_t)(sq * 4 + w) * BT + (size_t)b * T;

    __syncthreads();
    // ---- stage z0 (2 samples) ----
    if (tid < 128) {
        int ss = tid >> 6, c6 = tid & 63;
        zSm[ss][c6] = (_Float16)zout[(((size_t)(s0 + ss) * B + b) * T + 0) * 64 + c6];
    }
    __syncthreads();

    // ---- software-pipelined prefetch (t=1) ----
    float aN = *ap;
    float eN = 0.f;
    if (l < 32) eN = *ep;

    for (int t = 1; t < T; ++t) {
        const float aC = aN, eC = eN;

        // off-chain: store previous step's KL (red[] written pre-barrier(2)
        // of prev iter; all reads here precede barrier(1) => race-free)
        if (tid == 0 && t > 1) kp[t - 1] = 0.0625f * (red[0] + red[1] + red[2] + red[3]);

        // next-step global prefetch (consumed next iteration)
        if (t < T - 1) {
            ap += 128; aN = *ap;
            if (l < 32) { ep += (size_t)S * B * 64; eN = *ep; }
        }

        // ---- phase A MFMAs: z@W1b ; z@Wd1 ----
        const f16x8_t bz0 = *(const f16x8_t*)&zSm[lo][8 * hi];
        const f16x8_t bz1 = *(const f16x8_t*)&zSm[lo][32 + 8 * hi];

        f32x4_t acc1a = {0.f,0.f,0.f,0.f}, acc1b = {0.f,0.f,0.f,0.f}, acc3 = {0.f,0.f,0.f,0.f};
        acc1a = __builtin_amdgcn_mfma_f32_16x16x32_f16(a1[0][0], bz0, acc1a, 0, 0, 0);
        acc1b = __builtin_amdgcn_mfma_f32_16x16x32_f16(a1[1][0], bz0, acc1b, 0, 0, 0);
        acc3  = __builtin_amdgcn_mfma_f32_16x16x32_f16(a3[0],    bz0, acc3,  0, 0, 0);
        acc1a = __builtin_amdgcn_mfma_f32_16x16x32_f16(a1[0][1], bz1, acc1a, 0, 0, 0);
        acc1b = __builtin_amdgcn_mfma_f32_16x16x32_f16(a1[1][1], bz1, acc1b, 0, 0, 0);
        acc3  = __builtin_amdgcn_mfma_f32_16x16x32_f16(a3[1],    bz1, acc3,  0, 0, 0);

        // wave-private staging (same-wave LDS ordering; no barrier)
        if (prod) {
            *(f32x4_t*)&stH[lo][32 * w + 4 * hi]      = acc1a;
            *(f32x4_t*)&stH[lo][32 * w + 16 + 4 * hi] = acc1b;
            *(f32x4_t*)&stG[lo][16 * w + 4 * hi]      = acc3;
        }
        asm volatile("" ::: "memory");

        // ---- dense activation (same wave consumes its own strip) ----
        hidS[ha][hc] = (_Float16)fast_tanh(stH[ha][hc] + aC);
        if (l < 32)
            gS[ga][gc] = (_Float16)fast_tanh(stG[ga][gc] + bd1S[gc]);
        __syncthreads();   // (1) hid/g visible cross-wave

        // ---- phase B MFMAs: hid@W2 ; g@Wd2 ----
        const f16x8_t bh0 = *(const f16x8_t*)&hidS[lo][ 0 + 8 * hi];
        const f16x8_t bh1 = *(const f16x8_t*)&hidS[lo][32 + 8 * hi];
        const f16x8_t bh2 = *(const f16x8_t*)&hidS[lo][64 + 8 * hi];
        const f16x8_t bh3 = *(const f16x8_t*)&hidS[lo][96 + 8 * hi];
        const f16x8_t bg0 = *(const f16x8_t*)&gS[lo][8 * hi];
        const f16x8_t bg1 = *(const f16x8_t*)&gS[lo][32 + 8 * hi];

        f32x4_t accm = {0.f,0.f,0.f,0.f}, accp = {0.f,0.f,0.f,0.f}, acc4 = {0.f,0.f,0.f,0.f};
        accm = __builtin_amdgcn_mfma_f32_16x16x32_f16(a2[0][0], bh0, accm, 0, 0, 0);
        accp = __builtin_amdgcn_mfma_f32_16x16x32_f16(a2[1][0], bh0, accp, 0, 0, 0);
        acc4 = __builtin_amdgcn_mfma_f32_16x16x32_f16(a4[0],    bg0, acc4, 0, 0, 0);
        accm = __builtin_amdgcn_mfma_f32_16x16x32_f16(a2[0][1], bh1, accm, 0, 0, 0);
        accp = __builtin_amdgcn_mfma_f32_16x16x32_f16(a2[1][1], bh1, accp, 0, 0, 0);
        acc4 = __builtin_amdgcn_mfma_f32_16x16x32_f16(a4[1],    bg1, acc4, 0, 0, 0);
        accm = __builtin_amdgcn_mfma_f32_16x16x32_f16(a2[0][2], bh2, accm, 0, 0, 0);
        accp = __builtin_amdgcn_mfma_f32_16x16x32_f16(a2[1][2], bh2, accp, 0, 0, 0);
        accm = __builtin_amdgcn_mfma_f32_16x16x32_f16(a2[0][3], bh3, accm, 0, 0, 0);
        accp = __builtin_amdgcn_mfma_f32_16x16x32_f16(a2[1][3], bh3, accp, 0, 0, 0);

        if (prod) {
            *(f32x4_t*)&stM[lo][16 * w + 4 * hi]       = accm;
            *(f32x4_t*)&stM[lo][64 + 16 * w + 4 * hi]  = accp;
            *(f32x4_t*)&stMU[lo][16 * w + 4 * hi]      = acc4;
        }
        asm volatile("" ::: "memory");

        // ---- dense epilogue (same wave, lanes l<32: 2 samples x 16 cols) ----
        float term = 0.f;
        if (l < 32) {
            float m  = stM[es][ec] + bmS[ec];
            float P  = softplus_fast(stM[es][64 + ec] + bpS[ec]);
            float mu = stMU[es][ec] + bmuS[ec];
            float iq = invQS[ec];
            float z  = m + sqrtf(P) * eC;
            *zp = z; zp += 64;
            zSm[es][ec] = (_Float16)z;
            float d = m - mu;
            term = (P + d * d) * iq - __logf(P * iq) - 1.f;
        }
        term += __shfl_down(term, 16);
        term += __shfl_down(term, 8);
        term += __shfl_down(term, 4);
        term += __shfl_down(term, 2);
        term += __shfl_down(term, 1);
        if (l == 0) red[w] = term;
        __syncthreads();   // (2) zSm / red visible for next step
    }
    if (tid == 0) kp[T - 1] = 0.0625f * (red[0] + red[1] + red[2] + red[3]);
}

// ---------------------------------------------------------------------------
// Kernel P: projection + Poisson ell + m_stat.
// ---------------------------------------------------------------------------
__global__ __launch_bounds__(256) void kP(
        const float* __restrict__ zin, const float* __restrict__ C,
        const float* __restrict__ b_c, const float* __restrict__ y,
        float* __restrict__ m_stat, float* __restrict__ ell) {
    __shared__ float Cl[64 * 128];
    __shared__ float bc[128];
    __shared__ float ztl[64][8];
    __shared__ float red4[4];

    const int tid = threadIdx.x;
    {
        const float4* s = (const float4*)C;
        float4* d = (float4*)Cl;
        for (int i = tid; i < 2048; i += 256) d[i] = s[i];
    }
    if (tid < 128) bc[tid] = b_c[tid];

    const int bt0 = blockIdx.x * 8;
    const int n = tid & 127, shh = tid >> 7;

    for (int it = 0; it < 8; it++) {
        const int bt = bt0 + it;
        const int b = bt >> 8, t = bt & 255;
        __syncthreads();
        {
            int s_ = tid >> 6, l_ = tid & 63;
            ztl[l_][s_] = zin[(((size_t)s_ * B + b) * T + t) * 64 + l_];
            int i1 = tid + 256;
            s_ = i1 >> 6; l_ = i1 & 63;
            ztl[l_][s_] = zin[(((size_t)s_ * B + b) * T + t) * 64 + l_];
        }
        __syncthreads();
        if (tid < 64) {
            float4 a = *(const float4*)&ztl[tid][0];
            float4 bq = *(const float4*)&ztl[tid][4];
            m_stat[(size_t)bt * 64 + tid] =
                0.125f * (a.x + a.y + a.z + a.w + bq.x + bq.y + bq.z + bq.w);
        }
        float4 acc = {0.f, 0.f, 0.f, 0.f};
        #pragma unroll 4
        for (int k = 0; k < 64; k++) {
            float c = Cl[k * 128 + n];
            float4 z4 = *(const float4*)&ztl[k][shh * 4];
            acc.x += c * z4.x; acc.y += c * z4.y; acc.z += c * z4.z; acc.w += c * z4.w;
        }
        float bcv = bc[n];
        float yv = y[(size_t)bt * 128 + n];
        int yi = (int)yv;
        float ga = (yi < 2) ? 0.f
                 : ((yi == 2) ? 0.6931471805599453f
                 : ((yi == 3) ? 1.791759469228055f : 3.1780538303479458f));
        float term = 0.f;
        {
            float lr;
            lr = acc.x + bcv; term += yv * lr - __expf(lr) - ga;
            lr = acc.y + bcv; term += yv * lr - __expf(lr) - ga;
            lr = acc.z + bcv; term += yv * lr - __expf(lr) - ga;
            lr = acc.w + bcv; term += yv * lr - __expf(lr) - ga;
        }
        #pragma unroll
        for (int off = 32; off; off >>= 1) term += __shfl_down(term, off);
        if ((tid & 63) == 0) red4[tid >> 6] = term;
        __syncthreads();
        if (tid == 0) ell[bt] = 0.125f * (red4[0] + red4[1] + red4[2] + red4[3]);
    }
}

// ---------------------------------------------------------------------------
// Kernel R1/R2: two-stage loss reduction over 16 kl slabs + ell.
// ---------------------------------------------------------------------------
__global__ __launch_bounds__(256) void kR1(
        const float* __restrict__ klw, const float* __restrict__ ell,
        float* __restrict__ pw) {
    __shared__ float red4[4];
    const int tid = threadIdx.x;
    const int i0 = blockIdx.x * 512 + tid;
    float acc = 0.f;
    #pragma unroll
    for (int ii = 0; ii < 2; ii++) {
        int i = i0 + ii * 256;
        float v = -ell[i];
        #pragma unroll
        for (int sl = 0; sl < 16; sl++) v += klw[(size_t)sl * BT + i];
        acc += v;
    }
    #pragma unroll
    for (int off = 32; off; off >>= 1) acc += __shfl_down(acc, off);
    if ((tid & 63) == 0) red4[tid >> 6] = acc;
    __syncthreads();
    if (tid == 0) pw[blockIdx.x] = red4[0] + red4[1] + red4[2] + red4[3];
}

__global__ __launch_bounds__(64) void kR2(
        const float* __restrict__ pw, float* __restrict__ out0) {
    float v = pw[threadIdx.x];
    #pragma unroll
    for (int off = 32; off; off >>= 1) v += __shfl_down(v, off);
    if (threadIdx.x == 0) out0[0] = v * (1.0f / B);
}

// ---------------------------------------------------------------------------
extern "C" void kernel_launch(void* const* d_in, const int* in_sizes, int n_in,
                              void* d_out, int out_size, void* d_ws, size_t ws_size,
                              hipStream_t stream) {
    const float* y      = (const float*)d_in[0];
    const float* W_be   = (const float*)d_in[2];
    const float* b_be   = (const float*)d_in[3];
    const float* W_ic   = (const float*)d_in[4];
    const float* b_ic   = (const float*)d_in[5];
    const float* W_le1  = (const float*)d_in[6];
    const float* b_le1  = (const float*)d_in[7];
    const float* W_le2  = (const float*)d_in[8];
    const float* b_le2  = (const float*)d_in[9];
    const float* W_dyn1 = (const float*)d_in[10];
    const float* b_dyn1 = (const float*)d_in[11];
    const float* W_dyn2 = (const float*)d_in[12];
    const float* b_dyn2 = (const float*)d_in[13];
    const float* C      = (const float*)d_in[14];
    const float* b_c    = (const float*)d_in[15];
    const float* log_Q  = (const float*)d_in[16];
    const float* m_0    = (const float*)d_in[17];
    const float* log_Q_0= (const float*)d_in[18];
    const float* eps0   = (const float*)d_in[19];
    const float* eps    = (const float*)d_in[20];

    float* out = (float*)d_out;
    float* zo  = out + 1;
    float* ms  = out + 1 + (size_t)S * B * T * L;

    float* ws   = (float*)d_ws;
    float* klw  = ws;                                      // 16*B*T
    float* ellw = klw + (size_t)16 * BT;                   // B*T
    float* pw   = ellw + (size_t)BT;                       // 64
    float* h0   = pw + 64;                                 // B*128
    float* A    = h0 + (size_t)B * 128;                    // B*T*128

    kA<<<2048, 256, 0, stream>>>(y, W_be, b_be, W_le1, b_le1, A, h0);
    kB<<<128, 128, 0, stream>>>(h0, W_ic, b_ic, m_0, log_Q_0, eps0, zo, klw);
    kC<<<512, 256, 0, stream>>>(A, W_le1, W_le2, b_le2, W_dyn1, b_dyn1,
                                W_dyn2, b_dyn2, log_Q, eps, zo, klw);
    kP<<<4096, 256, 0, stream>>>(zo, C, b_c, y, ms, ellw);
    kR1<<<64, 256, 0, stream>>>(klw, ellw, pw);
    kR2<<<1, 64, 0, stream>>>(pw, out);
}

// Round 8
// 604.026 us; speedup vs baseline: 2.2928x; 1.0033x over previous
//
#include <hip/hip_runtime.h>

// Problem constants
constexpr int S = 8, B = 128, T = 256, N = 128;
constexpr int L = 64, Hh = 128, Hd = 64, Hl = 128;
constexpr int BT = B * T;

#define DEVFN __device__ __forceinline__

typedef float    f32x4_t __attribute__((ext_vector_type(4)));
typedef _Float16 f16x8_t __attribute__((ext_vector_type(8)));
typedef _Float16 f16x4_t __attribute__((ext_vector_type(4)));

DEVFN float softplus_f(float x) {            // accurate (prologue only)
    return (x > 0.f) ? (x + log1pf(expf(-x))) : log1pf(expf(x));
}
DEVFN float softplus_fast(float x) {         // branchless, native trans
    return fmaxf(x, 0.f) + __logf(1.f + __expf(-fabsf(x)));
}
DEVFN float fast_tanh(float x) {
    float ex = __builtin_exp2f(x * 2.885390081777927f);
    return 1.f - 2.f / (ex + 1.f);
}
DEVFN float gaOf(float yv) {                 // gammaln(y+1), y in {0..4}
    int yi = (int)yv;
    return (yi < 2) ? 0.f
         : ((yi == 2) ? 0.6931471805599453f
         : ((yi == 3) ? 1.791759469228055f : 3.1780538303479458f));
}

// ---------------------------------------------------------------------------
// Kernel A: per (b,t) row:  h = tanh(y @ W_be + b_be);  A = h @ W1a + b_le1
// ---------------------------------------------------------------------------
__global__ __launch_bounds__(256) void kA(
        const float* __restrict__ y,
        const float* __restrict__ W_be, const float* __restrict__ b_be,
        const float* __restrict__ W_le1, const float* __restrict__ b_le1,
        float* __restrict__ A, float* __restrict__ h0) {
    __shared__ float Wb[128 * 128];
    __shared__ float Wa[128 * 128];
    __shared__ float yt[128][16];
    __shared__ float ht[128][16];
    __shared__ float bbe[128], ble1[128];

    const int tid = threadIdx.x;
    {
        const float4* s1 = (const float4*)W_be;
        const float4* s2 = (const float4*)W_le1;   // rows 0..127 = W1a
        float4* d1 = (float4*)Wb;
        float4* d2 = (float4*)Wa;
        for (int i = tid; i < 4096; i += 256) { d1[i] = s1[i]; d2[i] = s2[i]; }
    }
    if (tid < 128) { bbe[tid] = b_be[tid]; ble1[tid] = b_le1[tid]; }

    const int bt0 = blockIdx.x * 16;
    {
        const float4* ys = (const float4*)(y + (size_t)bt0 * 128);
        for (int q = tid; q < 512; q += 256) {
            float4 v = ys[q];
            int r = q >> 5, n4 = (q & 31) * 4;
            yt[n4 + 0][r] = v.x; yt[n4 + 1][r] = v.y;
            yt[n4 + 2][r] = v.z; yt[n4 + 3][r] = v.w;
        }
    }
    __syncthreads();

    const int j = tid & 127, rh = tid >> 7;
    float acc[8];

    #pragma unroll
    for (int s = 0; s < 8; s++) acc[s] = bbe[j];
    #pragma unroll 4
    for (int k = 0; k < 128; k++) {
        float w = Wb[k * 128 + j];
        float4 a0 = *(const float4*)&yt[k][rh * 8];
        float4 a1 = *(const float4*)&yt[k][rh * 8 + 4];
        acc[0] += w * a0.x; acc[1] += w * a0.y; acc[2] += w * a0.z; acc[3] += w * a0.w;
        acc[4] += w * a1.x; acc[5] += w * a1.y; acc[6] += w * a1.z; acc[7] += w * a1.w;
    }
    #pragma unroll
    for (int s = 0; s < 8; s++) ht[j][rh * 8 + s] = tanhf(acc[s]);
    __syncthreads();

    #pragma unroll
    for (int s = 0; s < 8; s++) acc[s] = ble1[j];
    #pragma unroll 4
    for (int k = 0; k < 128; k++) {
        float w = Wa[k * 128 + j];
        float4 a0 = *(const float4*)&ht[k][rh * 8];
        float4 a1 = *(const float4*)&ht[k][rh * 8 + 4];
        acc[0] += w * a0.x; acc[1] += w * a0.y; acc[2] += w * a0.z; acc[3] += w * a0.w;
        acc[4] += w * a1.x; acc[5] += w * a1.y; acc[6] += w * a1.z; acc[7] += w * a1.w;
    }
    #pragma unroll
    for (int s = 0; s < 8; s++) {
        int r = rh * 8 + s;
        A[(size_t)(bt0 + r) * 128 + j] = acc[s];
    }
    if (rh == 0 && (bt0 & 255) == 0) {
        h0[(bt0 >> 8) * 128 + j] = ht[j][0];
    }
}

// ---------------------------------------------------------------------------
// Kernel B: initial step (t=0). Writes kl0 to slab 0, zeros slabs 1..15.
// ---------------------------------------------------------------------------
__global__ __launch_bounds__(128) void kB(
        const float* __restrict__ h0, const float* __restrict__ W_ic,
        const float* __restrict__ b_ic, const float* __restrict__ m_0,
        const float* __restrict__ log_Q_0, const float* __restrict__ eps0,
        float* __restrict__ zout, float* __restrict__ klw) {
    __shared__ float hr[128];
    __shared__ float mp[128];
    const int b = blockIdx.x, tid = threadIdx.x;
    hr[tid] = h0[b * 128 + tid];
    __syncthreads();
    float acc = b_ic[tid];
    #pragma unroll 8
    for (int k = 0; k < 128; k++) acc += hr[k] * W_ic[k * 128 + tid];
    mp[tid] = acc;
    __syncthreads();

    float term = 0.f;
    if (tid < 64) {
        float m = mp[tid];
        float P = softplus_f(mp[tid + 64]);
        float sq = sqrtf(P);
        #pragma unroll
        for (int s = 0; s < 8; s++) {
            float e = eps0[((size_t)s * B + b) * 64 + tid];
            zout[(((size_t)s * B + b) * T + 0) * 64 + tid] = m + sq * e;
        }
        float Q0 = softplus_f(log_Q_0[tid]);
        float d = m - m_0[tid];
        term = 0.5f * (logf(Q0) - logf(P) + (P + d * d) / Q0 - 1.f);
    }
    #pragma unroll
    for (int off = 32; off; off >>= 1) term += __shfl_down(term, off);
    if (tid == 0) klw[(size_t)b * T] = term;
    else if (tid < 16) klw[(size_t)tid * BT + (size_t)b * T] = 0.f;
}

// ---------------------------------------------------------------------------
// Kernel C (MFMA, NS=2, fused projection/ell): scan t=1..T-1.
// 512 blocks = (b = bid>>2, sq = bid&3 -> samples 2sq,2sq+1); 4 waves.
// MFMA convention (verified R2+): lane l: lo=l&15, hi=l>>4;
//   A[row=lo][k=8hi+e], B[k=8hi+e][col=lo]; D: col=lo(sample), row=4hi+reg.
// Lessons: NS=2 (grid = 2 blocks/CU cap); dense activation/epilogue;
// wave-local staging (2 barriers); no launch_bounds min-waves (R4 spill).
// NEW R8:
//  - LDS rows padded to 88/152 f16 (stride 44/76 dwords): b128 frag reads
//    were 8-way bank conflicts at stride 36/68 (2.0e7/dispatch), now ~2-way.
//  - Projection z@C + Poisson ell FUSED, reusing bz fragments (z_{t-1},
//    lagged): 4 extra MFMAs/wave off the recurrence chain; dense exp
//    epilogue slotted into phase-B MFMA latency gap; per-(sq,b,t) partials
//    to ellp slabs. kP kernel deleted.
// ---------------------------------------------------------------------------
__global__ __launch_bounds__(256) void kC(
        const float* __restrict__ Aglob,
        const float* __restrict__ W_le1, const float* __restrict__ W_le2,
        const float* __restrict__ b_le2,
        const float* __restrict__ W_dyn1, const float* __restrict__ b_dyn1,
        const float* __restrict__ W_dyn2, const float* __restrict__ b_dyn2,
        const float* __restrict__ log_Q, const float* __restrict__ eps,
        const float* __restrict__ Cmat, const float* __restrict__ b_c,
        const float* __restrict__ yglob,
        float* __restrict__ zout, float* __restrict__ klw,
        float* __restrict__ ellp) {
    __shared__ alignas(16) _Float16 zSm[16][88];    // rows 0,1 live; pad 44 dw
    __shared__ alignas(16) _Float16 hidS[16][152];  // pad 76 dw
    __shared__ alignas(16) _Float16 gS[16][88];
    __shared__ alignas(16) float stH[2][136];       // phase-A acc staging
    __shared__ alignas(16) float stG[2][72];
    __shared__ alignas(16) float stM[2][136];       // phase-B acc staging
    __shared__ alignas(16) float stMU[2][72];
    __shared__ alignas(16) float stE[2][136];       // projection staging
    __shared__ float bmS[64], bpS[64], bmuS[64], bd1S[64], invQS[64];
    __shared__ float bcS[128];
    __shared__ float red[4];
    __shared__ float redE[4][2];
    __shared__ float redT[4][2];

    const int tid = threadIdx.x;
    const int b = blockIdx.x >> 2, sq = blockIdx.x & 3, s0 = sq * 2;
    const int w = tid >> 6, l = tid & 63;
    const int lo = l & 15, hi = l >> 4;
    const bool prod = (lo < 2);         // producer lanes (valid D cols 0,1)

    // ---- zero f16 LDS (rows >=2 stay zero forever); fill const tables ----
    {
        _Float16* p1 = &zSm[0][0];
        _Float16* p2 = &hidS[0][0];
        _Float16* p3 = &gS[0][0];
        for (int i = tid; i < 16 * 88; i += 256) { p1[i] = (_Float16)0.f; p3[i] = (_Float16)0.f; }
        for (int i = tid; i < 16 * 152; i += 256) p2[i] = (_Float16)0.f;
    }
    if (tid < 64) {
        bmS[tid]   = b_le2[tid];
        bpS[tid]   = b_le2[64 + tid];
        bmuS[tid]  = b_dyn2[tid];
        bd1S[tid]  = b_dyn1[tid];
        invQS[tid] = 1.f / softplus_f(log_Q[tid]);
    }
    if (tid < 128) bcS[tid] = b_c[tid];

    // ---- static weight fragments ----
    f16x8_t a1[2][2], a2[2][4], a3[2], a4[2], aP[2][2];
    #pragma unroll
    for (int ct = 0; ct < 2; ++ct)
        #pragma unroll
        for (int kt = 0; kt < 2; ++kt) {
            f16x8_t f;
            #pragma unroll
            for (int e = 0; e < 8; ++e)
                f[e] = (_Float16)W_le1[(size_t)(128 + kt * 32 + 8 * hi + e) * 128 + (32 * w + 16 * ct + lo)];
            a1[ct][kt] = f;
        }
    #pragma unroll
    for (int ct = 0; ct < 2; ++ct) {
        const int col = (ct == 0 ? 16 * w : 64 + 16 * w) + lo;
        #pragma unroll
        for (int kt = 0; kt < 4; ++kt) {
            f16x8_t f;
            #pragma unroll
            for (int e = 0; e < 8; ++e)
                f[e] = (_Float16)W_le2[(size_t)(kt * 32 + 8 * hi + e) * 128 + col];
            a2[ct][kt] = f;
        }
    }
    #pragma unroll
    for (int kt = 0; kt < 2; ++kt) {
        f16x8_t f, g;
        #pragma unroll
        for (int e = 0; e < 8; ++e) {
            f[e] = (_Float16)W_dyn1[(size_t)(kt * 32 + 8 * hi + e) * 64 + (16 * w + lo)];
            g[e] = (_Float16)W_dyn2[(size_t)(kt * 32 + 8 * hi + e) * 64 + (16 * w + lo)];
        }
        a3[kt] = f; a4[kt] = g;
    }
    #pragma unroll
    for (int ct = 0; ct < 2; ++ct)
        #pragma unroll
        for (int kt = 0; kt < 2; ++kt) {
            f16x8_t f;
            #pragma unroll
            for (int e = 0; e < 8; ++e)
                f[e] = (_Float16)Cmat[(size_t)(kt * 32 + 8 * hi + e) * 128 + (32 * w + 16 * ct + lo)];
            aP[ct][kt] = f;
        }

    // ---- dense wave-local role mappings ----
    const int ha = l >> 5, hc = 32 * w + (l & 31);  // activation/proj: sample,col
    const int ga2 = (l >> 4) & 1, gc = 16 * w + (l & 15);
    const int es = ga2, ec = gc;                    // epilogue: sample,col
    const float* ap = Aglob + ((size_t)b * T + 1) * 128 + hc;
    const float* yp = yglob + ((size_t)b * T + 0) * 128 + hc;
    const float* ep = eps + (((size_t)(s0 + es)) * B + b) * 64 + ec;     // t=1
    float*       zp = zout + ((((size_t)(s0 + es)) * B + b) * T + 1) * 64 + ec;
    float*       kp = klw + (size_t)(sq * 4 + w) * BT + (size_t)b * T;
    float*       elp = ellp + (size_t)sq * BT + (size_t)b * T;

    __syncthreads();
    // ---- stage z0 (2 samples) ----
    if (tid < 128) {
        int ss = tid >> 6, c6 = tid & 63;
        zSm[ss][c6] = (_Float16)zout[(((size_t)(s0 + ss) * B + b) * T + 0) * 64 + c6];
    }
    __syncthreads();

    // ---- software-pipelined prefetch (t=1; y row for proj time 0) ----
    float aN = *ap;
    float yN = *yp;
    float eN = 0.f;
    if (l < 32) eN = *ep;

    for (int t = 1; t < T; ++t) {
        const float aC = aN, eC = eN, yC = yN;

        // off-chain: previous step's KL + lagged ell partial
        if (tid == 0) {
            if (t > 1) kp[t - 1] = 0.0625f * (red[0] + red[1] + red[2] + red[3]);
            if (t > 1) elp[t - 2] = redE[0][0] + redE[0][1] + redE[1][0] + redE[1][1]
                                  + redE[2][0] + redE[2][1] + redE[3][0] + redE[3][1];
        }

        // next-step global prefetch (consumed next iteration)
        yp += 128; yN = *yp;                       // y[b][t] (proj time t)
        if (t < T - 1) {
            ap += 128; aN = *ap;
            if (l < 32) { ep += (size_t)S * B * 64; eN = *ep; }
        }

        // ---- phase A MFMAs: z@W1b ; z@Wd1 ; (proj) z@C ----
        const f16x8_t bz0 = *(const f16x8_t*)&zSm[lo][8 * hi];
        const f16x8_t bz1 = *(const f16x8_t*)&zSm[lo][32 + 8 * hi];

        f32x4_t acc1a = {0.f,0.f,0.f,0.f}, acc1b = {0.f,0.f,0.f,0.f}, acc3 = {0.f,0.f,0.f,0.f};
        acc1a = __builtin_amdgcn_mfma_f32_16x16x32_f16(a1[0][0], bz0, acc1a, 0, 0, 0);
        acc1b = __builtin_amdgcn_mfma_f32_16x16x32_f16(a1[1][0], bz0, acc1b, 0, 0, 0);
        acc3  = __builtin_amdgcn_mfma_f32_16x16x32_f16(a3[0],    bz0, acc3,  0, 0, 0);
        acc1a = __builtin_amdgcn_mfma_f32_16x16x32_f16(a1[0][1], bz1, acc1a, 0, 0, 0);
        acc1b = __builtin_amdgcn_mfma_f32_16x16x32_f16(a1[1][1], bz1, acc1b, 0, 0, 0);
        acc3  = __builtin_amdgcn_mfma_f32_16x16x32_f16(a3[1],    bz1, acc3,  0, 0, 0);
        // projection of z_{t-1} (off the recurrence chain)
        f32x4_t accE0 = {0.f,0.f,0.f,0.f}, accE1 = {0.f,0.f,0.f,0.f};
        accE0 = __builtin_amdgcn_mfma_f32_16x16x32_f16(aP[0][0], bz0, accE0, 0, 0, 0);
        accE1 = __builtin_amdgcn_mfma_f32_16x16x32_f16(aP[1][0], bz0, accE1, 0, 0, 0);
        accE0 = __builtin_amdgcn_mfma_f32_16x16x32_f16(aP[0][1], bz1, accE0, 0, 0, 0);
        accE1 = __builtin_amdgcn_mfma_f32_16x16x32_f16(aP[1][1], bz1, accE1, 0, 0, 0);

        // wave-private staging (same-wave LDS ordering; no barrier)
        if (prod) {
            *(f32x4_t*)&stH[lo][32 * w + 4 * hi]      = acc1a;
            *(f32x4_t*)&stH[lo][32 * w + 16 + 4 * hi] = acc1b;
            *(f32x4_t*)&stG[lo][16 * w + 4 * hi]      = acc3;
        }
        asm volatile("" ::: "memory");

        // ---- dense activation (same wave consumes its own strip) ----
        hidS[ha][hc] = (_Float16)fast_tanh(stH[ha][hc] + aC);
        if (l < 32)
            gS[ga2][gc] = (_Float16)fast_tanh(stG[ga2][gc] + bd1S[gc]);
        __syncthreads();   // (1) hid/g visible cross-wave

        // ---- phase B MFMAs: hid@W2 ; g@Wd2 ----
        const f16x8_t bh0 = *(const f16x8_t*)&hidS[lo][ 0 + 8 * hi];
        const f16x8_t bh1 = *(const f16x8_t*)&hidS[lo][32 + 8 * hi];
        const f16x8_t bh2 = *(const f16x8_t*)&hidS[lo][64 + 8 * hi];
        const f16x8_t bh3 = *(const f16x8_t*)&hidS[lo][96 + 8 * hi];
        const f16x8_t bg0 = *(const f16x8_t*)&gS[lo][8 * hi];
        const f16x8_t bg1 = *(const f16x8_t*)&gS[lo][32 + 8 * hi];

        f32x4_t accm = {0.f,0.f,0.f,0.f}, accp = {0.f,0.f,0.f,0.f}, acc4 = {0.f,0.f,0.f,0.f};
        accm = __builtin_amdgcn_mfma_f32_16x16x32_f16(a2[0][0], bh0, accm, 0, 0, 0);
        accp = __builtin_amdgcn_mfma_f32_16x16x32_f16(a2[1][0], bh0, accp, 0, 0, 0);
        acc4 = __builtin_amdgcn_mfma_f32_16x16x32_f16(a4[0],    bg0, acc4, 0, 0, 0);
        accm = __builtin_amdgcn_mfma_f32_16x16x32_f16(a2[0][1], bh1, accm, 0, 0, 0);
        accp = __builtin_amdgcn_mfma_f32_16x16x32_f16(a2[1][1], bh1, accp, 0, 0, 0);
        acc4 = __builtin_amdgcn_mfma_f32_16x16x32_f16(a4[1],    bg1, acc4, 0, 0, 0);
        accm = __builtin_amdgcn_mfma_f32_16x16x32_f16(a2[0][2], bh2, accm, 0, 0, 0);
        accp = __builtin_amdgcn_mfma_f32_16x16x32_f16(a2[1][2], bh2, accp, 0, 0, 0);
        accm = __builtin_amdgcn_mfma_f32_16x16x32_f16(a2[0][3], bh3, accm, 0, 0, 0);
        accp = __builtin_amdgcn_mfma_f32_16x16x32_f16(a2[1][3], bh3, accp, 0, 0, 0);

        // ---- projection staging + dense ell epilogue (fills MFMA gap) ----
        if (prod) {
            *(f32x4_t*)&stE[lo][32 * w + 4 * hi]      = accE0;
            *(f32x4_t*)&stE[lo][32 * w + 16 + 4 * hi] = accE1;
        }
        asm volatile("" ::: "memory");
        {
            float lr = stE[ha][hc] + bcS[hc];
            float te = 0.125f * (yC * lr - __expf(lr));
            if (sq == 0 && ha == 0) te -= gaOf(yC);
            te += __shfl_down(te, 16);
            te += __shfl_down(te, 8);
            te += __shfl_down(te, 4);
            te += __shfl_down(te, 2);
            te += __shfl_down(te, 1);
            if ((l & 31) == 0) redE[w][ha] = te;
        }

        if (prod) {
            *(f32x4_t*)&stM[lo][16 * w + 4 * hi]       = accm;
            *(f32x4_t*)&stM[lo][64 + 16 * w + 4 * hi]  = accp;
            *(f32x4_t*)&stMU[lo][16 * w + 4 * hi]      = acc4;
        }
        asm volatile("" ::: "memory");

        // ---- dense epilogue (same wave, lanes l<32: 2 samples x 16 cols) ----
        float term = 0.f;
        if (l < 32) {
            float m  = stM[es][ec] + bmS[ec];
            float P  = softplus_fast(stM[es][64 + ec] + bpS[ec]);
            float mu = stMU[es][ec] + bmuS[ec];
            float iq = invQS[ec];
            float z  = m + sqrtf(P) * eC;
            *zp = z; zp += 64;
            zSm[es][ec] = (_Float16)z;
            float d = m - mu;
            term = (P + d * d) * iq - __logf(P * iq) - 1.f;
        }
        term += __shfl_down(term, 16);
        term += __shfl_down(term, 8);
        term += __shfl_down(term, 4);
        term += __shfl_down(term, 2);
        term += __shfl_down(term, 1);
        if (l == 0) red[w] = term;
        __syncthreads();   // (2) zSm / red / redE visible for next step
    }

    // ---- tail: final KL store, ell(T-2), projection of z_{T-1} ----
    if (tid == 0) {
        kp[T - 1] = 0.0625f * (red[0] + red[1] + red[2] + red[3]);
        elp[T - 2] = redE[0][0] + redE[0][1] + redE[1][0] + redE[1][1]
                   + redE[2][0] + redE[2][1] + redE[3][0] + redE[3][1];
    }
    {
        const f16x8_t bz0 = *(const f16x8_t*)&zSm[lo][8 * hi];
        const f16x8_t bz1 = *(const f16x8_t*)&zSm[lo][32 + 8 * hi];
        f32x4_t accE0 = {0.f,0.f,0.f,0.f}, accE1 = {0.f,0.f,0.f,0.f};
        accE0 = __builtin_amdgcn_mfma_f32_16x16x32_f16(aP[0][0], bz0, accE0, 0, 0, 0);
        accE1 = __builtin_amdgcn_mfma_f32_16x16x32_f16(aP[1][0], bz0, accE1, 0, 0, 0);
        accE0 = __builtin_amdgcn_mfma_f32_16x16x32_f16(aP[0][1], bz1, accE0, 0, 0, 0);
        accE1 = __builtin_amdgcn_mfma_f32_16x16x32_f16(aP[1][1], bz1, accE1, 0, 0, 0);
        if (prod) {
            *(f32x4_t*)&stE[lo][32 * w + 4 * hi]      = accE0;
            *(f32x4_t*)&stE[lo][32 * w + 16 + 4 * hi] = accE1;
        }
        asm volatile("" ::: "memory");
        float lr = stE[ha][hc] + bcS[hc];
        float te = 0.125f * (yN * lr - __expf(lr));
        if (sq == 0 && ha == 0) te -= gaOf(yN);
        te += __shfl_down(te, 16);
        te += __shfl_down(te, 8);
        te += __shfl_down(te, 4);
        te += __shfl_down(te, 2);
        te += __shfl_down(te, 1);
        if ((l & 31) == 0) redT[w][ha] = te;
        __syncthreads();
        if (tid == 0)
            elp[T - 1] = redT[0][0] + redT[0][1] + redT[1][0] + redT[1][1]
                       + redT[2][0] + redT[2][1] + redT[3][0] + redT[3][1];
    }
}

// ---------------------------------------------------------------------------
// Kernel M: m_stat = mean over s of z.  2048 blocks x 256 (float4 per thread).
// ---------------------------------------------------------------------------
__global__ __launch_bounds__(256) void kM(
        const float* __restrict__ zin, float* __restrict__ ms) {
    const int idx = blockIdx.x * 256 + threadIdx.x;     // over B*T*16 float4s
    const float4* z4 = (const float4*)zin;
    float4 acc = {0.f, 0.f, 0.f, 0.f};
    #pragma unroll
    for (int s = 0; s < 8; s++) {
        float4 v = z4[(size_t)s * BT * 16 + idx];
        acc.x += v.x; acc.y += v.y; acc.z += v.z; acc.w += v.w;
    }
    acc.x *= 0.125f; acc.y *= 0.125f; acc.z *= 0.125f; acc.w *= 0.125f;
    ((float4*)ms)[idx] = acc;
}

// ---------------------------------------------------------------------------
// Kernel R1/R2: two-stage loss reduction over 16 kl slabs + 4 ell slabs.
// ---------------------------------------------------------------------------
__global__ __launch_bounds__(256) void kR1(
        const float* __restrict__ klw, const float* __restrict__ ellp,
        float* __restrict__ pw) {
    __shared__ float red4[4];
    const int tid = threadIdx.x;
    const int i0 = blockIdx.x * 512 + tid;
    float acc = 0.f;
    #pragma unroll
    for (int ii = 0; ii < 2; ii++) {
        int i = i0 + ii * 256;
        float v = 0.f;
        #pragma unroll
        for (int sl = 0; sl < 16; sl++) v += klw[(size_t)sl * BT + i];
        #pragma unroll
        for (int sl = 0; sl < 4; sl++) v -= ellp[(size_t)sl * BT + i];
        acc += v;
    }
    #pragma unroll
    for (int off = 32; off; off >>= 1) acc += __shfl_down(acc, off);
    if ((tid & 63) == 0) red4[tid >> 6] = acc;
    __syncthreads();
    if (tid == 0) pw[blockIdx.x] = red4[0] + red4[1] + red4[2] + red4[3];
}

__global__ __launch_bounds__(64) void kR2(
        const float* __restrict__ pw, float* __restrict__ out0) {
    float v = pw[threadIdx.x];
    #pragma unroll
    for (int off = 32; off; off >>= 1) v += __shfl_down(v, off);
    if (threadIdx.x == 0) out0[0] = v * (1.0f / B);
}

// ---------------------------------------------------------------------------
extern "C" void kernel_launch(void* const* d_in, const int* in_sizes, int n_in,
                              void* d_out, int out_size, void* d_ws, size_t ws_size,
                              hipStream_t stream) {
    const float* y      = (const float*)d_in[0];
    const float* W_be   = (const float*)d_in[2];
    const float* b_be   = (const float*)d_in[3];
    const float* W_ic   = (const float*)d_in[4];
    const float* b_ic   = (const float*)d_in[5];
    const float* W_le1  = (const float*)d_in[6];
    const float* b_le1  = (const float*)d_in[7];
    const float* W_le2  = (const float*)d_in[8];
    const float* b_le2  = (const float*)d_in[9];
    const float* W_dyn1 = (const float*)d_in[10];
    const float* b_dyn1 = (const float*)d_in[11];
    const float* W_dyn2 = (const float*)d_in[12];
    const float* b_dyn2 = (const float*)d_in[13];
    const float* C      = (const float*)d_in[14];
    const float* b_c    = (const float*)d_in[15];
    const float* log_Q  = (const float*)d_in[16];
    const float* m_0    = (const float*)d_in[17];
    const float* log_Q_0= (const float*)d_in[18];
    const float* eps0   = (const float*)d_in[19];
    const float* eps    = (const float*)d_in[20];

    float* out = (float*)d_out;
    float* zo  = out + 1;
    float* ms  = out + 1 + (size_t)S * B * T * L;

    float* ws   = (float*)d_ws;
    float* klw  = ws;                                      // 16*B*T
    float* ellp = klw + (size_t)16 * BT;                   // 4*B*T
    float* pw   = ellp + (size_t)4 * BT;                   // 64
    float* h0   = pw + 64;                                 // B*128
    float* A    = h0 + (size_t)B * 128;                    // B*T*128

    kA<<<2048, 256, 0, stream>>>(y, W_be, b_be, W_le1, b_le1, A, h0);
    kB<<<128, 128, 0, stream>>>(h0, W_ic, b_ic, m_0, log_Q_0, eps0, zo, klw);
    kC<<<512, 256, 0, stream>>>(A, W_le1, W_le2, b_le2, W_dyn1, b_dyn1,
                                W_dyn2, b_dyn2, log_Q, eps, C, b_c, y,
                                zo, klw, ellp);
    kM<<<2048, 256, 0, stream>>>(zo, ms);
    kR1<<<64, 256, 0, stream>>>(klw, ellp, pw);
    kR2<<<1, 64, 0, stream>>>(pw, out);
}